// Round 15
// baseline (1320.799 us; speedup 1.0000x reference)
//
#include <hip/hip_runtime.h>
#include <hip/hip_bf16.h>
#include <math.h>

#define NB 8
#define NC 684
#define NH 16
#define NW 64
#define NHW 1024
#define NHID 256
#define NAD 512
#define NV 111
#define NT 36
#define KPAD 704

typedef __attribute__((ext_vector_type(8))) short bf16x8;
typedef __attribute__((ext_vector_type(4))) float f32x4;

__device__ __forceinline__ float wred_sum(float v){
  #pragma unroll
  for (int o = 32; o > 0; o >>= 1) v += __shfl_xor(v, o, 64);
  return v;
}
__device__ __forceinline__ float wred_max(float v){
  #pragma unroll
  for (int o = 32; o > 0; o >>= 1) v = fmaxf(v, __shfl_xor(v, o, 64));
  return v;
}
__device__ __forceinline__ float fsig(float x){ return 1.f/(1.f + __expf(-x)); }
__device__ __forceinline__ float ftanh(float x){ float e = __expf(2.f*x); return 1.f - 2.f/(e + 1.f); }
__device__ __forceinline__ unsigned short f2bf(float f){
  __hip_bfloat16 h = __float2bfloat16(f);
  return *(unsigned short*)&h;
}
__device__ __forceinline__ float bf2f(unsigned short u){
  return __uint_as_float(((unsigned)u) << 16);
}

// ---------------- P0
__global__ void k_p0(const float* __restrict__ im, float* __restrict__ dmask,
                     float* __restrict__ msum, float* __restrict__ ys, float* __restrict__ xs,
                     float* __restrict__ idt, float* __restrict__ abuf)
{
  const int tid = threadIdx.x;
  for (int i = tid; i < NB*NHW; i += 256){
    int b = i >> 10, hw = i & 1023; int h = hw >> 6, w = hw & 63;
    dmask[i] = im[b*(256*1024) + (h*16)*1024 + (w*16)];
    abuf[i] = 0.f;
  }
  if (tid < 128) idt[tid] = expf(-(float)tid * (9.210340371976184f/128.f));
  __syncthreads();
  if (tid < 8){
    float s = 0.f;
    for (int i = 0; i < NHW; i++) s += dmask[tid*NHW + i];
    msum[tid] = s;
  }
  for (int p = tid; p < NB*NW; p += 256){
    int b = p >> 6, w = p & 63;
    float tot = 0.f;
    for (int h = 0; h < NH; h++) tot += dmask[b*NHW + h*64 + w];
    float inv = 6.283185307179586f/(tot + 1e-6f);
    float run = 0.f;
    for (int h = 0; h < NH; h++){ run += dmask[b*NHW + h*64 + w]; ys[b*NHW + h*64 + w] = run*inv; }
  }
  for (int p = tid; p < NB*NH; p += 256){
    int b = p >> 4, h = p & 15;
    float tot = 0.f;
    for (int w = 0; w < NW; w++) tot += dmask[b*NHW + h*64 + w];
    float inv = 6.283185307179586f/(tot + 1e-6f);
    float run = 0.f;
    for (int w = 0; w < NW; w++){ run += dmask[b*NHW + h*64 + w]; xs[b*NHW + h*64 + w] = run*inv; }
  }
}

// ---------------- P1: masked average
__global__ void k_avg(const float* __restrict__ cnn, const float* __restrict__ dmask,
                      const float* __restrict__ msum, float* __restrict__ avg)
{
  int gid = blockIdx.x*blockDim.x + threadIdx.x;
  int gw = gid >> 6, lane = gid & 63;
  int nw = (gridDim.x*blockDim.x) >> 6;
  for (int ow = gw; ow < NB*NC; ow += nw){
    int b = ow / NC;
    const float* base = cnn + (size_t)ow * NHW;
    const float* dm = dmask + b*NHW;
    float s = 0.f;
    for (int i = lane; i < NHW; i += 64) s += base[i]*dm[i];
    s = wred_sum(s);
    if (lane == 0) avg[ow] = s / msum[b];
  }
}

// ---------------- P2: hidden(-1) + counting_ctx
__global__ void k_init(const float* __restrict__ avg, const float* __restrict__ iW, const float* __restrict__ ib,
                       const float* __restrict__ cp, const float* __restrict__ cW, const float* __restrict__ cb,
                       float* __restrict__ hm1, float* __restrict__ cctx)
{
  int gid = blockIdx.x*blockDim.x + threadIdx.x;
  int gw = gid >> 6, lane = gid & 63;
  int nw = (gridDim.x*blockDim.x) >> 6;
  for (int ow = gw; ow < 2*NB*NHID; ow += nw){
    if (ow < NB*NHID){
      int b = ow >> 8, j = ow & 255;
      float s = 0.f;
      for (int k = lane; k < NC; k += 64) s += avg[b*NC + k]*iW[j*NC + k];
      s = wred_sum(s);
      if (lane == 0) hm1[ow] = tanhf(s + ib[j]);
    } else {
      int o = ow - NB*NHID; int b = o >> 8, j = o & 255;
      float s = 0.f;
      for (int k = lane; k < NV; k += 64) s += cp[b*NV + k]*cW[j*NV + k];
      s = wred_sum(s);
      if (lane == 0) cctx[o] = s + cb[j];
    }
  }
}

// ---------------- P3a: cnnT[b][hw][c] bf16
__global__ __launch_bounds__(256) void k_cvt(const float* __restrict__ cnn, unsigned short* __restrict__ cnnT)
{
  const int hw0 = blockIdx.x << 6, c0 = blockIdx.y << 6, b = blockIdx.z;  // (16, 11, 8)
  __shared__ float T[64][65];
  const int tid = threadIdx.x;
  #pragma unroll
  for (int u = 0; u < 16; u++){
    int idx = tid + (u<<8);
    int cc = idx >> 6, mm = idx & 63;
    int c = c0 + cc;
    T[cc][mm] = (c < NC) ? cnn[((size_t)b*NC + c)*NHW + hw0 + mm] : 0.f;
  }
  __syncthreads();
  #pragma unroll
  for (int r0 = 0; r0 < 64; r0 += 8){
    int hwl = r0 + (tid >> 5);
    int cp = (tid & 31) << 1;
    unsigned u0 = f2bf(T[cp][hwl]);
    unsigned u1 = f2bf(T[cp+1][hwl]);
    *(unsigned*)&cnnT[((size_t)((b<<10) + hw0 + hwl))*KPAD + c0 + cp] = (u1 << 16) | u0;
  }
}

// ---------------- P3b: ewb[d][c] bf16 padded
__global__ void k_cvtw(const float* __restrict__ ew, unsigned short* __restrict__ ewb)
{
  int x = blockIdx.x*256 + threadIdx.x;
  if (x >= NAD*KPAD) return;
  int d = x / KPAD, c = x - d*KPAD;
  float v = (c < NC) ? ew[(size_t)d*NC + c] : 0.f;
  ewb[x] = f2bf(v);
}

// ---------------- P3c: trans(bf16) = MFMA GEMM + bias + pos-emb; LDS-coalesced stores
__global__ __launch_bounds__(256) void k_mma_trans(const unsigned short* __restrict__ cnnT,
    const unsigned short* __restrict__ ewb, const float* __restrict__ eb,
    const float* __restrict__ ys, const float* __restrict__ xs,
    const float* __restrict__ idt, unsigned short* __restrict__ transb)
{
  const int m0 = blockIdx.x << 7;
  const int n0 = blockIdx.y << 6;
  const int b = m0 >> 10, hw0 = m0 & 1023;
  const int tid = threadIdx.x, lane = tid & 63, wv = tid >> 6;
  __shared__ unsigned short ts[128*66];
  const int kgrp = (lane >> 4) << 3;
  const unsigned short* arow0 = cnnT + ((size_t)((b<<10) + hw0 + (wv<<5) + (lane & 15)))*KPAD + kgrp;
  const unsigned short* arow1 = arow0 + (size_t)16*KPAD;
  f32x4 acc[2][4];
  #pragma unroll
  for (int mt=0; mt<2; mt++)
    #pragma unroll
    for (int s = 0; s < 4; s++){ acc[mt][s][0]=0.f; acc[mt][s][1]=0.f; acc[mt][s][2]=0.f; acc[mt][s][3]=0.f; }
  #pragma unroll 2
  for (int k0 = 0; k0 < KPAD; k0 += 32){
    bf16x8 a0 = *(const bf16x8*)(arow0 + k0);
    bf16x8 a1 = *(const bf16x8*)(arow1 + k0);
    #pragma unroll
    for (int s = 0; s < 4; s++){
      const unsigned short* brow = ewb + (size_t)(n0 + (s<<4) + (lane & 15))*KPAD + kgrp + k0;
      bf16x8 bf = *(const bf16x8*)brow;
      acc[0][s] = __builtin_amdgcn_mfma_f32_16x16x32_bf16(a0, bf, acc[0][s], 0, 0, 0);
      acc[1][s] = __builtin_amdgcn_mfma_f32_16x16x32_bf16(a1, bf, acc[1][s], 0, 0, 0);
    }
  }
  #pragma unroll
  for (int mt = 0; mt < 2; mt++){
    #pragma unroll
    for (int r = 0; r < 4; r++){
      int l = (wv<<5) + (mt<<4) + ((lane>>4)<<2) + r;
      int hw = hw0 + l;
      float ysv = ys[(b<<10)+hw], xsv = xs[(b<<10)+hw];
      #pragma unroll
      for (int s = 0; s < 4; s++){
        int d = n0 + (s<<4) + (lane & 15);
        float idtv = (d < 256) ? idt[d>>1] : idt[(d-256)>>1];
        float base = (d < 256) ? ysv : xsv;
        float arg = base*idtv;
        float pe = (d & 1) ? cosf(arg) : sinf(arg);
        ts[l*66 + (s<<4) + (lane & 15)] = f2bf(acc[mt][s][r] + eb[d] + pe);
      }
    }
  }
  __syncthreads();
  // coalesced copy: 128 rows x 32 u32
  const unsigned* ts32 = (const unsigned*)ts;
  unsigned* dst32 = (unsigned*)transb;
  #pragma unroll
  for (int k = 0; k < 16; k++){
    int i = tid + (k<<8);
    int row = i >> 5, col = i & 31;
    dst32[((size_t)((b<<10) + hw0 + row))*256 + (n0>>1) + col] = ts32[row*33 + col];
  }
}

// ---------------- P4a: per-word projections giW[v][768], embwW[v][256]
__global__ __launch_bounds__(256) void k_wproj(const float* __restrict__ emb, const float* __restrict__ wih,
    const float* __restrict__ bih, const float* __restrict__ ewW, const float* __restrict__ ewb2,
    float* __restrict__ giW, float* __restrict__ embwW)
{
  const int v = blockIdx.x, g = blockIdx.y;  // (111, 4)
  const int tid = threadIdx.x;
  __shared__ float er[256];
  er[tid] = emb[(size_t)v*256 + tid];
  __syncthreads();
  if (g < 3){
    int i = (g<<8) + tid;
    float s = 0.f;
    const float* wr = wih + (size_t)i*256;
    #pragma unroll 4
    for (int k = 0; k < 256; k++) s += er[k]*wr[k];
    giW[(size_t)v*768 + i] = s + bih[i];
  } else {
    float s = 0.f;
    const float* wr = ewW + (size_t)tid*256;
    #pragma unroll 4
    for (int k = 0; k < 256; k++) s += er[k]*wr[k];
    embwW[(size_t)v*256 + tid] = s + ewb2[tid];
  }
}

// ---------------- P4b: embwOW[v][u] = embwW[v]·oW[u]
__global__ __launch_bounds__(128) void k_ewo(const float* __restrict__ embwW, const float* __restrict__ oW,
                                             float* __restrict__ embwOW)
{
  const int v = blockIdx.x;
  const int u = threadIdx.x;
  __shared__ float ew[256];
  ew[u] = embwW[(size_t)v*256 + u];
  ew[128 + u] = embwW[(size_t)v*256 + 128 + u];
  __syncthreads();
  if (u < NV){
    float s = 0.f;
    const float* wr = oW + (size_t)u*256;
    #pragma unroll 4
    for (int k = 0; k < 256; k++) s += ew[k]*wr[k];
    embwOW[v*NV + u] = s;
  }
}

// ---------------- P5: MtT[d][tap] bf16, taps padded to 128
__global__ void k_mt(const float* __restrict__ aw, const float* __restrict__ acw, unsigned short* __restrict__ MtT)
{
  __shared__ float col[512];
  int t = blockIdx.x; int tid = threadIdx.x;   // 121 x 256
  for (int c = tid; c < 512; c += 256) col[c] = acw[(size_t)c*121 + t];
  __syncthreads();
  for (int d = tid; d < 512; d += 256){
    float s = 0.f;
    const float4* r4 = (const float4*)(aw + (size_t)d*512);
    for (int k = 0; k < 128; k++){
      float4 w = r4[k];
      s += col[k*4+0]*w.x + col[k*4+1]*w.y + col[k*4+2]*w.z + col[k*4+3]*w.w;
    }
    MtT[d*128 + t] = f2bf(s);
    if (t == 0){
      #pragma unroll
      for (int p = 121; p < 128; p++) MtT[d*128 + p] = 0;
    }
  }
}

// ---------------- P6: SO = oW@sW; CB
__global__ __launch_bounds__(256) void k_so(const float* __restrict__ sW, const float* __restrict__ oW,
    const float* __restrict__ sb, const float* __restrict__ cxb, const float* __restrict__ cctx,
    const float* __restrict__ ob, float* __restrict__ SO, float* __restrict__ CB)
{
  const int v = blockIdx.x; const int tid = threadIdx.x;
  float acc = 0.f;
  for (int j = 0; j < 256; j++) acc += sW[(size_t)j*256 + tid] * oW[(size_t)v*256 + j];
  SO[(size_t)v*256 + tid] = acc;
  if (tid < 8){
    float s = ob[v];
    for (int j = 0; j < 256; j++) s += (sb[j] + cxb[j] + cctx[tid*256 + j]) * oW[(size_t)v*256 + j];
    CB[tid*NV + v] = s;
  }
}

// ---------------- P8: COb[v][c] bf16
__global__ __launch_bounds__(256) void k_co(const float* __restrict__ cxW, const float* __restrict__ oW,
                                            unsigned short* __restrict__ COb)
{
  const int c = blockIdx.x*256 + threadIdx.x;
  const int v = blockIdx.y;       // 0..127
  if (c >= KPAD) return;
  float acc = 0.f;
  if (v < NV && c < NC){
    for (int j = 0; j < 256; j++) acc += cxW[(size_t)j*NC + c] * oW[(size_t)v*256 + j];
  }
  COb[(size_t)v*KPAD + c] = f2bf(acc);
}

// ---------------- P9: PO = MFMA GEMM
__global__ __launch_bounds__(256) void k_mma_PO(const unsigned short* __restrict__ cnnT,
    const unsigned short* __restrict__ COb, float* __restrict__ PO)
{
  const int m0 = blockIdx.x << 6;
  const int n0 = blockIdx.y << 6;
  const int b = blockIdx.z;
  const int tid = threadIdx.x, lane = tid & 63, wv = tid >> 6;
  const int mrow = m0 + (wv<<4) + (lane & 15);
  const int kgrp = (lane >> 4) << 3;
  const unsigned short* arow = cnnT + ((size_t)((b<<10) + mrow))*KPAD + kgrp;
  f32x4 acc[4];
  #pragma unroll
  for (int s = 0; s < 4; s++){ acc[s][0]=0.f; acc[s][1]=0.f; acc[s][2]=0.f; acc[s][3]=0.f; }
  #pragma unroll 2
  for (int k0 = 0; k0 < KPAD; k0 += 32){
    bf16x8 af = *(const bf16x8*)(arow + k0);
    #pragma unroll
    for (int s = 0; s < 4; s++){
      const unsigned short* brow = COb + (size_t)(n0 + (s<<4) + (lane & 15))*KPAD + kgrp + k0;
      bf16x8 bf = *(const bf16x8*)brow;
      acc[s] = __builtin_amdgcn_mfma_f32_16x16x32_bf16(af, bf, acc[s], 0, 0, 0);
    }
  }
  #pragma unroll
  for (int s = 0; s < 4; s++){
    int v = n0 + (s<<4) + (lane & 15);
    #pragma unroll
    for (int r = 0; r < 4; r++){
      int hw = m0 + (wv<<4) + ((lane>>4)<<2) + r;
      PO[(((size_t)b*128 + v)<<10) + hw] = acc[s][r];
    }
  }
}

// ---------------- gru slice helper — prologue only (fp32)
__device__ __forceinline__ void gru_slice(const float* __restrict__ hs, const float* __restrict__ whh,
    const float* __restrict__ bhh, const float* __restrict__ gg, float* __restrict__ hdst,
    int r, int wid, int lane)
{
  #pragma unroll 1
  for (int jj = 0; jj < 8; jj++){
    int j = (r<<6) + (wid<<3) + jj;
    float sr = 0.f, sz = 0.f, sn = 0.f;
    #pragma unroll
    for (int u = 0; u < 4; u++){
      int k = lane + (u<<6);
      float hv = hs[k];
      sr += hv * whh[(size_t)j*256 + k];
      sz += hv * whh[(size_t)(j+256)*256 + k];
      sn += hv * whh[(size_t)(j+512)*256 + k];
    }
    sr = wred_sum(sr); sz = wred_sum(sz); sn = wred_sum(sn);
    if (lane == 0){
      float rr = 1.f/(1.f + expf(-(gg[j] + sr + bhh[j])));
      float zz = 1.f/(1.f + expf(-(gg[j+256] + sz + bhh[j+256])));
      float nn = tanhf(gg[j+512] + rr*(sn + bhh[j+512]));
      hdst[j] = (1.f - zz)*nn + zz*hs[j];
    }
  }
}

// ---------------- P10: initial GRU (word0 = 1)
__global__ __launch_bounds__(512) void k_gq0(const float* __restrict__ hm1, const float* __restrict__ whh,
    const float* __restrict__ bhh, const float* __restrict__ giW, float* __restrict__ hbuf3)
{
  const int r = blockIdx.x, b = blockIdx.y;
  const int tid = threadIdx.x, lane = tid & 63, wid = tid >> 6;
  __shared__ float hs[256];
  if (tid < 256) hs[tid] = hm1[(b<<8) + tid];
  __syncthreads();
  gru_slice(hs, whh, bhh, giW + 768, hbuf3 + (b<<8), r, wid, lane);
}

// ---------------- P12: bf16 weights for in-loop gru/query
// whhTjb[(g*256+j)*128 + kp] = pair {w[2kp], w[2kp+1]};  ahWTr[d][k] plain bf16
__global__ void k_tr(const float* __restrict__ whh, const float* __restrict__ ahW,
                     __hip_bfloat162* __restrict__ whhTjb, unsigned short* __restrict__ ahWTr)
{
  int i = blockIdx.x*256 + threadIdx.x;
  int stride = gridDim.x*256;
  for (int x = i; x < 3*256*128; x += stride){
    int kp = x & 127, j = (x >> 7) & 255, g = x >> 15;
    float lo = whh[(size_t)((g<<8)+j)*256 + (kp<<1)];
    float hi = whh[(size_t)((g<<8)+j)*256 + (kp<<1) + 1];
    __hip_bfloat162 h2; h2.x = __float2bfloat16(lo); h2.y = __float2bfloat16(hi);
    whhTjb[x] = h2;
  }
  for (int x = i; x < 512*256; x += stride){
    ahWTr[x] = f2bf(ahW[x]);
  }
}

// ================= per-step kernel: 256 thr, grid 512 (2 blocks/CU), t = 0..NT =================
// block (b=gid>>6, seg=gid&63, h=seg>>2, w0=(seg&3)<<4): 16 w-columns
//  [t>0] softmax(e(t-1)); (seg==0) A(t) write; (seg<32) prob(t-1) all 4 waves
//  [t<NT] halo + inline query (2 d/thread) + im2col + MFMA stencil + epilogue -> e(t)
//  (seg<16, t<NT-1) gru slice: 16 j per block
__global__ __launch_bounds__(256) void k_step(
  const float* __restrict__ dmask, const unsigned short* __restrict__ MtT,
  const unsigned short* __restrict__ transb,
  const float* __restrict__ acvW, const float* __restrict__ acvb,
  const float* __restrict__ PO, const float* __restrict__ SO,
  const float* __restrict__ CB, const float* __restrict__ embwOW,
  const float* __restrict__ giW, const int* __restrict__ lab,
  const __hip_bfloat162* __restrict__ whhTjb,
  const float* __restrict__ bhh, const unsigned short* __restrict__ ahWTr,
  const float* __restrict__ ahb, float* __restrict__ hbuf3,
  float* __restrict__ abuf, float* __restrict__ ebuf,
  float* __restrict__ out, int t)
{
  const int gid = blockIdx.x, tid = threadIdx.x;
  const int lane = tid & 63, wv = tid >> 6;
  const int b = gid >> 6, seg = gid & 63, h = seg >> 2, w0 = (seg & 3) << 4;
  __shared__ float eo[16][516];
  __shared__ float al[1024];
  __shared__ float as4[11][28];
  __shared__ unsigned short Asb[16*136];
  __shared__ float hq[256];
  __shared__ float qs[512];
  __shared__ float red[10];

  const float* eprev = ebuf + (((t+1)&1)<<13);
  float*       ecurb = ebuf + ((t&1)<<13);
  const float* aprev = abuf + (((t+1)&1)<<13);
  float*       acur  = abuf + ((t&1)<<13);

  if (t < NT) hq[tid] = hbuf3[(t%3)*2048 + (b<<8) + tid];

  if (t > 0){
    // ---- softmax(e(t-1)) -> al (4 elems/thread)
    float e[4], dm[4];
    #pragma unroll
    for (int k = 0; k < 4; k++){
      e[k] = eprev[(b<<10) + tid + (k<<8)];
      dm[k] = dmask[(b<<10) + tid + (k<<8)];
    }
    float m = fmaxf(fmaxf(e[0], e[1]), fmaxf(e[2], e[3]));
    m = wred_max(m);
    if (lane == 0) red[wv] = m;
    __syncthreads();
    if (tid == 0) red[8] = fmaxf(fmaxf(red[0], red[1]), fmaxf(red[2], red[3]));
    __syncthreads();
    float g = red[8];
    float x[4]; float s = 0.f;
    #pragma unroll
    for (int k = 0; k < 4; k++){ x[k] = __expf(e[k] - g)*dm[k]; s += x[k]; }
    s = wred_sum(s);
    if (lane == 0) red[wv] = s;
    __syncthreads();
    if (tid == 0) red[9] = red[0] + red[1] + red[2] + red[3];
    __syncthreads();
    float inv = 1.f/(red[9] + 1e-10f);
    #pragma unroll
    for (int k = 0; k < 4; k++) al[tid + (k<<8)] = x[k]*inv;
    __syncthreads();
    if (seg == 0 && t < NT){
      #pragma unroll
      for (int k = 0; k < 4; k++){
        int p = tid + (k<<8);
        acur[(b<<10)+p] = aprev[(b<<10)+p] + al[p];
      }
    }
    // ---- prob(t-1): blocks seg<32, v = seg + 32*wv
    if (seg < 32){
      int v = seg + (wv<<5);
      if (v < NV){
        int wprev = (t-1 == 0) ? 1 : lab[b*NT + t - 2];
        const float* POr = PO + (((size_t)b*128 + v)<<10);
        const float* hr = hbuf3 + ((t-1)%3)*2048 + (b<<8);
        const float* SOr = SO + (size_t)v*256;
        float a2 = 0.f;
        #pragma unroll
        for (int u = 0; u < 16; u++){ int p = lane + (u<<6); a2 += al[p]*POr[p]; }
        #pragma unroll
        for (int u = 0; u < 4; u++){ int k = lane + (u<<6); a2 += hr[k]*SOr[k]; }
        a2 = wred_sum(a2);
        if (lane == 0)
          out[((size_t)b*NT + (t-1))*NV + v] = a2 + CB[b*NV + v] + embwOW[wprev*NV + v];
      }
    }
  }
  if (t < NT){
    // ---- halo: as4[11][26 used]
    for (int idx = tid; idx < 11*28; idx += 256){
      int r = idx/28, c = idx - r*28;
      float v = 0.f;
      if (t > 0 && c < 26){
        int hi2 = h + r - 5, wi = w0 + c - 5;
        if ((unsigned)hi2 < 16u && (unsigned)wi < 64u){
          int p = (hi2<<6) + wi;
          v = aprev[(b<<10)+p] + al[p];
        }
      }
      as4[r][c] = v;
    }
    // ---- inline query: d = tid and tid+256 (bf16x8 row loads)
    {
      const unsigned short* ar0 = ahWTr + (size_t)tid*256;
      const unsigned short* ar1 = ahWTr + (size_t)(tid+256)*256;
      float s0 = 0.f, s1 = 0.f;
      #pragma unroll 8
      for (int g8 = 0; g8 < 32; g8++){
        bf16x8 wa = *(const bf16x8*)(ar0 + (g8<<3));
        bf16x8 wb = *(const bf16x8*)(ar1 + (g8<<3));
        #pragma unroll
        for (int i = 0; i < 8; i++){
          float hv = hq[(g8<<3) + i];
          s0 += hv*bf2f((unsigned short)wa[i]);
          s1 += hv*bf2f((unsigned short)wb[i]);
        }
      }
      qs[tid] = s0 + ahb[tid];
      qs[tid+256] = s1 + ahb[tid+256];
    }
    __syncthreads();
    // ---- im2col: Asb[16 w][128 taps] bf16 (pitch 136)
    #pragma unroll
    for (int u = 0; u < 8; u++){
      int idx = tid + (u<<8);
      int w = idx >> 7, tap = idx & 127;
      float v = 0.f;
      if (tap < 121 && t > 0){
        int ki = tap/11, kj = tap - ki*11;
        v = as4[ki][w + kj];
      }
      Asb[w*136 + tap] = f2bf(v);
    }
    __syncthreads();
    // ---- MFMA stencil: E[16w][512d]; wave wv owns 128-d slice
    const int kg = (lane >> 4) << 3;
    f32x4 acc[8];
    #pragma unroll
    for (int s = 0; s < 8; s++){ acc[s][0]=0.f; acc[s][1]=0.f; acc[s][2]=0.f; acc[s][3]=0.f; }
    if (t > 0){
      const unsigned short* ab = &Asb[(lane & 15)*136 + kg];
      #pragma unroll
      for (int k0 = 0; k0 < 128; k0 += 32){
        bf16x8 af = *(const bf16x8*)(ab + k0);
        #pragma unroll
        for (int s = 0; s < 8; s++){
          const unsigned short* brow = MtT + (size_t)((wv<<7) + (s<<4) + (lane & 15))*128 + kg + k0;
          bf16x8 bf = *(const bf16x8*)brow;
          acc[s] = __builtin_amdgcn_mfma_f32_16x16x32_bf16(af, bf, acc[s], 0, 0, 0);
        }
      }
    }
    // ---- epilogue
    const float acb0 = acvb[0];
    #pragma unroll
    for (int s = 0; s < 8; s++){
      int d = (wv<<7) + (s<<4) + (lane & 15);
      float wav = acvW[d];
      float qd = qs[d];
      #pragma unroll
      for (int r = 0; r < 4; r++){
        int w = ((lane>>4)<<2) + r;
        int hw = (h<<6) + w0 + w;
        float tv = bf2f(transb[((size_t)((b<<10)+hw))*NAD + d]);
        eo[w][d] = wav * ftanh(qd + tv + acc[s][r]);
      }
    }
    __syncthreads();
    // ---- reduce: wave wv owns w = wv*4..+3
    float* ecur = ecurb + (b<<10) + (h<<6) + w0;
    #pragma unroll
    for (int k = 0; k < 4; k++){
      int w = (wv<<2) + k;
      float sum = 0.f;
      #pragma unroll
      for (int u = 0; u < 8; u++) sum += eo[w][lane + (u<<6)];
      sum = wred_sum(sum);
      if (lane == 0) ecur[w] = sum + acb0;
    }
    // ---- gru: blocks seg<16 compute j = seg*16 + wv*4 + (lane>>4); 16-lane k-split
    if (seg < 16 && t < NT-1){
      int j = (seg<<4) + (wv<<2) + (lane>>4);
      int qg = lane & 15;
      const __hip_bfloat162* r0 = whhTjb + (size_t)j*128 + (qg<<3);
      const __hip_bfloat162* r1 = whhTjb + (size_t)(256+j)*128 + (qg<<3);
      const __hip_bfloat162* r2 = whhTjb + (size_t)(512+j)*128 + (qg<<3);
      float sr = 0.f, sz = 0.f, sn = 0.f;
      #pragma unroll
      for (int i = 0; i < 8; i++){
        int kp = (qg<<3) + i;
        float h0 = hq[kp<<1], h1 = hq[(kp<<1)+1];
        __hip_bfloat162 wr = r0[i], wz2 = r1[i], wn = r2[i];
        sr += h0*__bfloat162float(wr.x) + h1*__bfloat162float(wr.y);
        sz += h0*__bfloat162float(wz2.x) + h1*__bfloat162float(wz2.y);
        sn += h0*__bfloat162float(wn.x) + h1*__bfloat162float(wn.y);
      }
      #pragma unroll
      for (int o = 1; o < 16; o <<= 1){
        sr += __shfl_xor(sr, o, 64);
        sz += __shfl_xor(sz, o, 64);
        sn += __shfl_xor(sn, o, 64);
      }
      if (qg == 0){
        int wnext = lab[b*NT + t];
        const float* gg = giW + (size_t)wnext*768;
        float r = fsig(gg[j] + sr + bhh[j]);
        float z = fsig(gg[j+256] + sz + bhh[j+256]);
        float n = ftanh(gg[j+512] + r*(sn + bhh[j+512]));
        hbuf3[((t+1)%3)*2048 + (b<<8) + j] = (1.f - z)*n + z*hq[j];
      }
    }
  }
}

extern "C" void kernel_launch(void* const* d_in, const int* in_sizes, int n_in,
                              void* d_out, int out_size, void* d_ws, size_t ws_size,
                              hipStream_t stream)
{
  const float* cnn  = (const float*)d_in[0];
  const float* cp   = (const float*)d_in[1];
  const float* im   = (const float*)d_in[2];
  const float* iW   = (const float*)d_in[3];
  const float* ib   = (const float*)d_in[4];
  const float* emb  = (const float*)d_in[5];
  const float* wih  = (const float*)d_in[6];
  const float* whh  = (const float*)d_in[7];
  const float* bih  = (const float*)d_in[8];
  const float* bhh  = (const float*)d_in[9];
  const float* ahW  = (const float*)d_in[10];
  const float* ahb  = (const float*)d_in[11];
  const float* acw  = (const float*)d_in[12];
  const float* awW  = (const float*)d_in[13];
  const float* acvW = (const float*)d_in[14];
  const float* acvb = (const float*)d_in[15];
  const float* ecw  = (const float*)d_in[16];
  const float* ecb  = (const float*)d_in[17];
  const float* sW   = (const float*)d_in[18];
  const float* sb   = (const float*)d_in[19];
  const float* ewW  = (const float*)d_in[20];
  const float* ewb2 = (const float*)d_in[21];
  const float* cxW  = (const float*)d_in[22];
  const float* cxb  = (const float*)d_in[23];
  const float* cW   = (const float*)d_in[24];
  const float* cb   = (const float*)d_in[25];
  const float* oW   = (const float*)d_in[26];
  const float* ob   = (const float*)d_in[27];
  const int*   lab  = (const int*)d_in[28];
  float* out = (float*)d_out;
  float* ws = (float*)d_ws;

  float* dmask  = ws + 0;        // 8192
  float* ys     = ws + 8192;     // 8192
  float* xs     = ws + 16384;    // 8192
  float* idt    = ws + 24576;    // 128
  float* msum   = ws + 24704;    // 16
  float* avg    = ws + 24720;    // 5472
  float* cctx   = ws + 30192;    // 2048
  float* hm1    = ws + 32240;    // 2048
  float* hbuf3  = ws + 34288;    // 6144
  float* abuf   = ws + 40432;    // 16384
  float* ebuf   = ws + 56816;    // 16384
  float* giW    = ws + 73200;    // 85248
  float* embwW  = ws + 158448;   // 28416
  float* embwOW = ws + 186864;   // 12352
  unsigned short* MtT = (unsigned short*)(ws + 199216);   // 32768 words
  float* SO     = ws + 231984;   // 28416
  float* CB     = ws + 260400;   // 896
  __hip_bfloat162* whhTjb = (__hip_bfloat162*)(ws + 261296);  // 98304 words
  unsigned short* ahWTr  = (unsigned short*)(ws + 359600);    // 65536 words
  unsigned short* cnnT = (unsigned short*)(ws + 425136);  // 2883584 words
  unsigned short* ewbb = (unsigned short*)(ws + 3308720); // 180224 words
  unsigned short* COb  = (unsigned short*)(ws + 3488944); // 45056 words
  unsigned short* transb = (unsigned short*)(ws + 3534000); // 2097152 words
  float* PO     = ws + 5631152;  // 4194304  (total ~39.3 MB)

  k_p0<<<1, 256, 0, stream>>>(im, dmask, msum, ys, xs, idt, abuf);
  k_avg<<<456, 256, 0, stream>>>(cnn, dmask, msum, avg);
  k_init<<<256, 256, 0, stream>>>(avg, iW, ib, cp, cW, cb, hm1, cctx);
  k_wproj<<<dim3(NV, 4), 256, 0, stream>>>(emb, wih, bih, ewW, ewb2, giW, embwW);
  k_ewo<<<NV, 128, 0, stream>>>(embwW, oW, embwOW);
  k_cvt<<<dim3(16, 11, 8), 256, 0, stream>>>(cnn, cnnT);
  k_cvtw<<<(NAD*KPAD + 255)/256, 256, 0, stream>>>(ecw, ewbb);
  k_mma_trans<<<dim3(64, 8), 256, 0, stream>>>(cnnT, ewbb, ecb, ys, xs, idt, transb);
  k_mt<<<121, 256, 0, stream>>>(awW, acw, MtT);
  k_so<<<NV, 256, 0, stream>>>(sW, oW, sb, cxb, cctx, ob, SO, CB);
  k_co<<<dim3(3, 128), 256, 0, stream>>>(cxW, oW, COb);
  k_mma_PO<<<dim3(16, 2, 8), 256, 0, stream>>>(cnnT, COb, PO);
  k_tr<<<128, 256, 0, stream>>>(whh, ahW, whhTjb, ahWTr);
  k_gq0<<<dim3(4, 8), 512, 0, stream>>>(hm1, whh, bhh, giW, hbuf3);

  for (int t = 0; t <= NT; t++){
    k_step<<<512, 256, 0, stream>>>(dmask, MtT, transb, acvW, acvb, PO, SO, CB, embwOW,
                                    giW, lab, whhTjb, bhh, ahWTr, ahb, hbuf3, abuf, ebuf, out, t);
  }
}

// Round 16
// 1088.989 us; speedup vs baseline: 1.2129x; 1.2129x over previous
//
#include <hip/hip_runtime.h>
#include <hip/hip_bf16.h>
#include <math.h>

#define NB 8
#define NC 684
#define NH 16
#define NW 64
#define NHW 1024
#define NHID 256
#define NAD 512
#define NV 111
#define NT 36
#define KPAD 704

typedef __attribute__((ext_vector_type(8))) short bf16x8;
typedef __attribute__((ext_vector_type(4))) float f32x4;

__device__ __forceinline__ float wred_sum(float v){
  #pragma unroll
  for (int o = 32; o > 0; o >>= 1) v += __shfl_xor(v, o, 64);
  return v;
}
__device__ __forceinline__ float wred_max(float v){
  #pragma unroll
  for (int o = 32; o > 0; o >>= 1) v = fmaxf(v, __shfl_xor(v, o, 64));
  return v;
}
__device__ __forceinline__ float fsig(float x){ return 1.f/(1.f + __expf(-x)); }
__device__ __forceinline__ float ftanh(float x){ float e = __expf(2.f*x); return 1.f - 2.f/(e + 1.f); }
__device__ __forceinline__ unsigned short f2bf(float f){
  __hip_bfloat16 h = __float2bfloat16(f);
  return *(unsigned short*)&h;
}
__device__ __forceinline__ float bf2f(unsigned short u){
  return __uint_as_float(((unsigned)u) << 16);
}

// ---------------- P0
__global__ void k_p0(const float* __restrict__ im, float* __restrict__ dmask,
                     float* __restrict__ msum, float* __restrict__ ys, float* __restrict__ xs,
                     float* __restrict__ idt, float* __restrict__ abuf)
{
  const int tid = threadIdx.x;
  for (int i = tid; i < NB*NHW; i += 256){
    int b = i >> 10, hw = i & 1023; int h = hw >> 6, w = hw & 63;
    dmask[i] = im[b*(256*1024) + (h*16)*1024 + (w*16)];
    abuf[i] = 0.f;
  }
  if (tid < 128) idt[tid] = expf(-(float)tid * (9.210340371976184f/128.f));
  __syncthreads();
  if (tid < 8){
    float s = 0.f;
    for (int i = 0; i < NHW; i++) s += dmask[tid*NHW + i];
    msum[tid] = s;
  }
  for (int p = tid; p < NB*NW; p += 256){
    int b = p >> 6, w = p & 63;
    float tot = 0.f;
    for (int h = 0; h < NH; h++) tot += dmask[b*NHW + h*64 + w];
    float inv = 6.283185307179586f/(tot + 1e-6f);
    float run = 0.f;
    for (int h = 0; h < NH; h++){ run += dmask[b*NHW + h*64 + w]; ys[b*NHW + h*64 + w] = run*inv; }
  }
  for (int p = tid; p < NB*NH; p += 256){
    int b = p >> 4, h = p & 15;
    float tot = 0.f;
    for (int w = 0; w < NW; w++) tot += dmask[b*NHW + h*64 + w];
    float inv = 6.283185307179586f/(tot + 1e-6f);
    float run = 0.f;
    for (int w = 0; w < NW; w++){ run += dmask[b*NHW + h*64 + w]; xs[b*NHW + h*64 + w] = run*inv; }
  }
}

// ---------------- P1: masked average
__global__ void k_avg(const float* __restrict__ cnn, const float* __restrict__ dmask,
                      const float* __restrict__ msum, float* __restrict__ avg)
{
  int gid = blockIdx.x*blockDim.x + threadIdx.x;
  int gw = gid >> 6, lane = gid & 63;
  int nw = (gridDim.x*blockDim.x) >> 6;
  for (int ow = gw; ow < NB*NC; ow += nw){
    int b = ow / NC;
    const float* base = cnn + (size_t)ow * NHW;
    const float* dm = dmask + b*NHW;
    float s = 0.f;
    for (int i = lane; i < NHW; i += 64) s += base[i]*dm[i];
    s = wred_sum(s);
    if (lane == 0) avg[ow] = s / msum[b];
  }
}

// ---------------- P2: hidden(-1) + counting_ctx
__global__ void k_init(const float* __restrict__ avg, const float* __restrict__ iW, const float* __restrict__ ib,
                       const float* __restrict__ cp, const float* __restrict__ cW, const float* __restrict__ cb,
                       float* __restrict__ hm1, float* __restrict__ cctx)
{
  int gid = blockIdx.x*blockDim.x + threadIdx.x;
  int gw = gid >> 6, lane = gid & 63;
  int nw = (gridDim.x*blockDim.x) >> 6;
  for (int ow = gw; ow < 2*NB*NHID; ow += nw){
    if (ow < NB*NHID){
      int b = ow >> 8, j = ow & 255;
      float s = 0.f;
      for (int k = lane; k < NC; k += 64) s += avg[b*NC + k]*iW[j*NC + k];
      s = wred_sum(s);
      if (lane == 0) hm1[ow] = tanhf(s + ib[j]);
    } else {
      int o = ow - NB*NHID; int b = o >> 8, j = o & 255;
      float s = 0.f;
      for (int k = lane; k < NV; k += 64) s += cp[b*NV + k]*cW[j*NV + k];
      s = wred_sum(s);
      if (lane == 0) cctx[o] = s + cb[j];
    }
  }
}

// ---------------- P3a: cnnT[b][hw][c] bf16
__global__ __launch_bounds__(256) void k_cvt(const float* __restrict__ cnn, unsigned short* __restrict__ cnnT)
{
  const int hw0 = blockIdx.x << 6, c0 = blockIdx.y << 6, b = blockIdx.z;  // (16, 11, 8)
  __shared__ float T[64][65];
  const int tid = threadIdx.x;
  #pragma unroll
  for (int u = 0; u < 16; u++){
    int idx = tid + (u<<8);
    int cc = idx >> 6, mm = idx & 63;
    int c = c0 + cc;
    T[cc][mm] = (c < NC) ? cnn[((size_t)b*NC + c)*NHW + hw0 + mm] : 0.f;
  }
  __syncthreads();
  #pragma unroll
  for (int r0 = 0; r0 < 64; r0 += 8){
    int hwl = r0 + (tid >> 5);
    int cp = (tid & 31) << 1;
    unsigned u0 = f2bf(T[cp][hwl]);
    unsigned u1 = f2bf(T[cp+1][hwl]);
    *(unsigned*)&cnnT[((size_t)((b<<10) + hw0 + hwl))*KPAD + c0 + cp] = (u1 << 16) | u0;
  }
}

// ---------------- P3b: ewb[d][c] bf16 padded
__global__ void k_cvtw(const float* __restrict__ ew, unsigned short* __restrict__ ewb)
{
  int x = blockIdx.x*256 + threadIdx.x;
  if (x >= NAD*KPAD) return;
  int d = x / KPAD, c = x - d*KPAD;
  float v = (c < NC) ? ew[(size_t)d*NC + c] : 0.f;
  ewb[x] = f2bf(v);
}

// ---------------- P3c: trans(bf16) = MFMA GEMM + bias + pos-emb; 2 m-tiles/wave (R14 version)
__global__ __launch_bounds__(256) void k_mma_trans(const unsigned short* __restrict__ cnnT,
    const unsigned short* __restrict__ ewb, const float* __restrict__ eb,
    const float* __restrict__ ys, const float* __restrict__ xs,
    const float* __restrict__ idt, unsigned short* __restrict__ transb)
{
  const int m0 = blockIdx.x << 7;
  const int n0 = blockIdx.y << 6;
  const int b = m0 >> 10, hw0 = m0 & 1023;
  const int tid = threadIdx.x, lane = tid & 63, wv = tid >> 6;
  const int kgrp = (lane >> 4) << 3;
  const unsigned short* arow0 = cnnT + ((size_t)((b<<10) + hw0 + (wv<<5) + (lane & 15)))*KPAD + kgrp;
  const unsigned short* arow1 = arow0 + (size_t)16*KPAD;
  f32x4 acc[2][4];
  #pragma unroll
  for (int mt=0; mt<2; mt++)
    #pragma unroll
    for (int s = 0; s < 4; s++){ acc[mt][s][0]=0.f; acc[mt][s][1]=0.f; acc[mt][s][2]=0.f; acc[mt][s][3]=0.f; }
  #pragma unroll 2
  for (int k0 = 0; k0 < KPAD; k0 += 32){
    bf16x8 a0 = *(const bf16x8*)(arow0 + k0);
    bf16x8 a1 = *(const bf16x8*)(arow1 + k0);
    #pragma unroll
    for (int s = 0; s < 4; s++){
      const unsigned short* brow = ewb + (size_t)(n0 + (s<<4) + (lane & 15))*KPAD + kgrp + k0;
      bf16x8 bf = *(const bf16x8*)brow;
      acc[0][s] = __builtin_amdgcn_mfma_f32_16x16x32_bf16(a0, bf, acc[0][s], 0, 0, 0);
      acc[1][s] = __builtin_amdgcn_mfma_f32_16x16x32_bf16(a1, bf, acc[1][s], 0, 0, 0);
    }
  }
  #pragma unroll
  for (int mt = 0; mt < 2; mt++){
    #pragma unroll
    for (int r = 0; r < 4; r++){
      int hw = hw0 + (wv<<5) + (mt<<4) + ((lane>>4)<<2) + r;
      float ysv = ys[(b<<10)+hw], xsv = xs[(b<<10)+hw];
      #pragma unroll
      for (int s = 0; s < 4; s++){
        int d = n0 + (s<<4) + (lane & 15);
        float idtv = (d < 256) ? idt[d>>1] : idt[(d-256)>>1];
        float base = (d < 256) ? ysv : xsv;
        float arg = base*idtv;
        float pe = (d & 1) ? cosf(arg) : sinf(arg);
        transb[((size_t)((b<<10)+hw))*NAD + d] = f2bf(acc[mt][s][r] + eb[d] + pe);
      }
    }
  }
}

// ---------------- P4a: per-word projections giW[v][768], embwW[v][256]
__global__ __launch_bounds__(256) void k_wproj(const float* __restrict__ emb, const float* __restrict__ wih,
    const float* __restrict__ bih, const float* __restrict__ ewW, const float* __restrict__ ewb2,
    float* __restrict__ giW, float* __restrict__ embwW)
{
  const int v = blockIdx.x, g = blockIdx.y;  // (111, 4)
  const int tid = threadIdx.x;
  __shared__ float er[256];
  er[tid] = emb[(size_t)v*256 + tid];
  __syncthreads();
  if (g < 3){
    int i = (g<<8) + tid;
    float s = 0.f;
    const float* wr = wih + (size_t)i*256;
    #pragma unroll 4
    for (int k = 0; k < 256; k++) s += er[k]*wr[k];
    giW[(size_t)v*768 + i] = s + bih[i];
  } else {
    float s = 0.f;
    const float* wr = ewW + (size_t)tid*256;
    #pragma unroll 4
    for (int k = 0; k < 256; k++) s += er[k]*wr[k];
    embwW[(size_t)v*256 + tid] = s + ewb2[tid];
  }
}

// ---------------- P4b: embwOW[v][u] = embwW[v]·oW[u]
__global__ __launch_bounds__(128) void k_ewo(const float* __restrict__ embwW, const float* __restrict__ oW,
                                             float* __restrict__ embwOW)
{
  const int v = blockIdx.x;
  const int u = threadIdx.x;
  __shared__ float ew[256];
  ew[u] = embwW[(size_t)v*256 + u];
  ew[128 + u] = embwW[(size_t)v*256 + 128 + u];
  __syncthreads();
  if (u < NV){
    float s = 0.f;
    const float* wr = oW + (size_t)u*256;
    #pragma unroll 4
    for (int k = 0; k < 256; k++) s += ew[k]*wr[k];
    embwOW[v*NV + u] = s;
  }
}

// ---------------- P5: MtT[d][tap] bf16, taps padded to 128
__global__ void k_mt(const float* __restrict__ aw, const float* __restrict__ acw, unsigned short* __restrict__ MtT)
{
  __shared__ float col[512];
  int t = blockIdx.x; int tid = threadIdx.x;   // 121 x 256
  for (int c = tid; c < 512; c += 256) col[c] = acw[(size_t)c*121 + t];
  __syncthreads();
  for (int d = tid; d < 512; d += 256){
    float s = 0.f;
    const float4* r4 = (const float4*)(aw + (size_t)d*512);
    for (int k = 0; k < 128; k++){
      float4 w = r4[k];
      s += col[k*4+0]*w.x + col[k*4+1]*w.y + col[k*4+2]*w.z + col[k*4+3]*w.w;
    }
    MtT[d*128 + t] = f2bf(s);
    if (t == 0){
      #pragma unroll
      for (int p = 121; p < 128; p++) MtT[d*128 + p] = 0;
    }
  }
}

// ---------------- P6: SO = oW@sW; CB
__global__ __launch_bounds__(256) void k_so(const float* __restrict__ sW, const float* __restrict__ oW,
    const float* __restrict__ sb, const float* __restrict__ cxb, const float* __restrict__ cctx,
    const float* __restrict__ ob, float* __restrict__ SO, float* __restrict__ CB)
{
  const int v = blockIdx.x; const int tid = threadIdx.x;
  float acc = 0.f;
  for (int j = 0; j < 256; j++) acc += sW[(size_t)j*256 + tid] * oW[(size_t)v*256 + j];
  SO[(size_t)v*256 + tid] = acc;
  if (tid < 8){
    float s = ob[v];
    for (int j = 0; j < 256; j++) s += (sb[j] + cxb[j] + cctx[tid*256 + j]) * oW[(size_t)v*256 + j];
    CB[tid*NV + v] = s;
  }
}

// ---------------- P8: COb[v][c] bf16
__global__ __launch_bounds__(256) void k_co(const float* __restrict__ cxW, const float* __restrict__ oW,
                                            unsigned short* __restrict__ COb)
{
  const int c = blockIdx.x*256 + threadIdx.x;
  const int v = blockIdx.y;       // 0..127
  if (c >= KPAD) return;
  float acc = 0.f;
  if (v < NV && c < NC){
    for (int j = 0; j < 256; j++) acc += cxW[(size_t)j*NC + c] * oW[(size_t)v*256 + j];
  }
  COb[(size_t)v*KPAD + c] = f2bf(acc);
}

// ---------------- P9: PO = MFMA GEMM
__global__ __launch_bounds__(256) void k_mma_PO(const unsigned short* __restrict__ cnnT,
    const unsigned short* __restrict__ COb, float* __restrict__ PO)
{
  const int m0 = blockIdx.x << 6;
  const int n0 = blockIdx.y << 6;
  const int b = blockIdx.z;
  const int tid = threadIdx.x, lane = tid & 63, wv = tid >> 6;
  const int mrow = m0 + (wv<<4) + (lane & 15);
  const int kgrp = (lane >> 4) << 3;
  const unsigned short* arow = cnnT + ((size_t)((b<<10) + mrow))*KPAD + kgrp;
  f32x4 acc[4];
  #pragma unroll
  for (int s = 0; s < 4; s++){ acc[s][0]=0.f; acc[s][1]=0.f; acc[s][2]=0.f; acc[s][3]=0.f; }
  #pragma unroll 2
  for (int k0 = 0; k0 < KPAD; k0 += 32){
    bf16x8 af = *(const bf16x8*)(arow + k0);
    #pragma unroll
    for (int s = 0; s < 4; s++){
      const unsigned short* brow = COb + (size_t)(n0 + (s<<4) + (lane & 15))*KPAD + kgrp + k0;
      bf16x8 bf = *(const bf16x8*)brow;
      acc[s] = __builtin_amdgcn_mfma_f32_16x16x32_bf16(af, bf, acc[s], 0, 0, 0);
    }
  }
  #pragma unroll
  for (int s = 0; s < 4; s++){
    int v = n0 + (s<<4) + (lane & 15);
    #pragma unroll
    for (int r = 0; r < 4; r++){
      int hw = m0 + (wv<<4) + ((lane>>4)<<2) + r;
      PO[(((size_t)b*128 + v)<<10) + hw] = acc[s][r];
    }
  }
}

// ---------------- gru slice helper — prologue only (fp32)
__device__ __forceinline__ void gru_slice(const float* __restrict__ hs, const float* __restrict__ whh,
    const float* __restrict__ bhh, const float* __restrict__ gg, float* __restrict__ hdst,
    int r, int wid, int lane)
{
  #pragma unroll 1
  for (int jj = 0; jj < 8; jj++){
    int j = (r<<6) + (wid<<3) + jj;
    float sr = 0.f, sz = 0.f, sn = 0.f;
    #pragma unroll
    for (int u = 0; u < 4; u++){
      int k = lane + (u<<6);
      float hv = hs[k];
      sr += hv * whh[(size_t)j*256 + k];
      sz += hv * whh[(size_t)(j+256)*256 + k];
      sn += hv * whh[(size_t)(j+512)*256 + k];
    }
    sr = wred_sum(sr); sz = wred_sum(sz); sn = wred_sum(sn);
    if (lane == 0){
      float rr = 1.f/(1.f + expf(-(gg[j] + sr + bhh[j])));
      float zz = 1.f/(1.f + expf(-(gg[j+256] + sz + bhh[j+256])));
      float nn = tanhf(gg[j+512] + rr*(sn + bhh[j+512]));
      hdst[j] = (1.f - zz)*nn + zz*hs[j];
    }
  }
}

// ---------------- P10: initial GRU (word0 = 1)
__global__ __launch_bounds__(512) void k_gq0(const float* __restrict__ hm1, const float* __restrict__ whh,
    const float* __restrict__ bhh, const float* __restrict__ giW, float* __restrict__ hbuf3)
{
  const int r = blockIdx.x, b = blockIdx.y;
  const int tid = threadIdx.x, lane = tid & 63, wid = tid >> 6;
  __shared__ float hs[256];
  if (tid < 256) hs[tid] = hm1[(b<<8) + tid];
  __syncthreads();
  gru_slice(hs, whh, bhh, giW + 768, hbuf3 + (b<<8), r, wid, lane);
}

// ---------------- P12: bf16-packed weights for in-loop gru/query
__global__ void k_tr(const float* __restrict__ whh, const float* __restrict__ ahW,
                     __hip_bfloat162* __restrict__ whhTjb, __hip_bfloat162* __restrict__ ahWTb)
{
  int i = blockIdx.x*256 + threadIdx.x;
  int stride = gridDim.x*256;
  for (int x = i; x < 3*256*128; x += stride){
    int kp = x & 127, j = (x >> 7) & 255, g = x >> 15;
    float lo = whh[(size_t)((g<<8)+j)*256 + (kp<<1)];
    float hi = whh[(size_t)((g<<8)+j)*256 + (kp<<1) + 1];
    __hip_bfloat162 h2; h2.x = __float2bfloat16(lo); h2.y = __float2bfloat16(hi);
    whhTjb[x] = h2;
  }
  for (int x = i; x < 128*512; x += stride){
    int d = x & 511, kp = x >> 9;
    float lo = ahW[(size_t)d*256 + (kp<<1)];
    float hi = ahW[(size_t)d*256 + (kp<<1) + 1];
    __hip_bfloat162 h2; h2.x = __float2bfloat16(lo); h2.y = __float2bfloat16(hi);
    ahWTb[x] = h2;
  }
}

// ================= per-step kernel: grid 256 (1 block/CU), 512 thr, t = 0..NT =================
// R14 structure; query hoisted to top, transb prefetched before MFMA.
__global__ __launch_bounds__(512) void k_step(
  const float* __restrict__ dmask, const unsigned short* __restrict__ MtT,
  const unsigned short* __restrict__ transb,
  const float* __restrict__ acvW, const float* __restrict__ acvb,
  const float* __restrict__ PO, const float* __restrict__ SO,
  const float* __restrict__ CB, const float* __restrict__ embwOW,
  const float* __restrict__ giW, const int* __restrict__ lab,
  const __hip_bfloat162* __restrict__ whhTjb,
  const float* __restrict__ bhh, const __hip_bfloat162* __restrict__ ahWTb,
  const float* __restrict__ ahb, float* __restrict__ hbuf3,
  float* __restrict__ abuf, float* __restrict__ ebuf,
  float* __restrict__ out, int t)
{
  const int gid = blockIdx.x, tid = threadIdx.x;
  const int lane = tid & 63, wv = tid >> 6;
  const int b = gid >> 5, seg = gid & 31, h = seg >> 1, w0 = (seg & 1) << 5;
  __shared__ float eo[32][516];
  __shared__ float al[1024];
  __shared__ float as4[11][44];
  __shared__ unsigned short Asb[32*136];
  __shared__ float hq[256];
  __shared__ float qs[512];
  __shared__ float red[18];

  const float* eprev = ebuf + (((t+1)&1)<<13);
  float*       ecurb = ebuf + ((t&1)<<13);
  const float* aprev = abuf + (((t+1)&1)<<13);
  float*       acur  = abuf + ((t&1)<<13);

  if (t < NT && tid < 256) hq[tid] = hbuf3[(t%3)*2048 + (b<<8) + tid];
  __syncthreads();

  // ---- inline query hoisted to top (overlaps with softmax below via wave interleave)
  if (t < NT){
    float s2 = 0.f;
    #pragma unroll 4
    for (int kp = 0; kp < 128; kp++){
      __hip_bfloat162 w = ahWTb[(kp<<9) + tid];
      s2 += hq[kp<<1]*__bfloat162float(w.x) + hq[(kp<<1)+1]*__bfloat162float(w.y);
    }
    qs[tid] = s2 + ahb[tid];
  }

  if (t > 0){
    // ---- softmax(e(t-1)) -> al
    float e0 = eprev[(b<<10)+tid], e1 = eprev[(b<<10)+512+tid];
    float dm0 = dmask[(b<<10)+tid], dm1 = dmask[(b<<10)+512+tid];
    float m = wred_max(fmaxf(e0, e1));
    if (lane == 0) red[wv] = m;
    __syncthreads();
    if (tid == 0){
      float g = red[0];
      #pragma unroll
      for (int k = 1; k < 8; k++) g = fmaxf(g, red[k]);
      red[16] = g;
    }
    __syncthreads();
    float g = red[16];
    float x0 = __expf(e0 - g)*dm0, x1 = __expf(e1 - g)*dm1;
    float s = wred_sum(x0 + x1);
    if (lane == 0) red[wv] = s;
    __syncthreads();
    if (tid == 0){
      float ss = 0.f;
      #pragma unroll
      for (int k = 0; k < 8; k++) ss += red[k];
      red[17] = ss;
    }
    __syncthreads();
    float inv = 1.f/(red[17] + 1e-10f);
    al[tid] = x0*inv; al[512+tid] = x1*inv;
    __syncthreads();
    if (seg == 0 && t < NT){
      acur[(b<<10)+tid]     = aprev[(b<<10)+tid]     + al[tid];
      acur[(b<<10)+512+tid] = aprev[(b<<10)+512+tid] + al[512+tid];
    }
    // ---- prob(t-1): waves 0..3, v = seg + 32*wv
    if (wv < 4){
      int v = seg + (wv<<5);
      if (v < NV){
        int wprev = (t-1 == 0) ? 1 : lab[b*NT + t - 2];
        const float* POr = PO + (((size_t)b*128 + v)<<10);
        const float* hr = hbuf3 + ((t-1)%3)*2048 + (b<<8);
        const float* SOr = SO + (size_t)v*256;
        float a2 = 0.f;
        #pragma unroll
        for (int u = 0; u < 16; u++){ int p = lane + (u<<6); a2 += al[p]*POr[p]; }
        #pragma unroll
        for (int u = 0; u < 4; u++){ int k = lane + (u<<6); a2 += hr[k]*SOr[k]; }
        a2 = wred_sum(a2);
        if (lane == 0)
          out[((size_t)b*NT + (t-1))*NV + v] = a2 + CB[b*NV + v] + embwOW[wprev*NV + v];
      }
    }
  }
  if (t < NT){
    // ---- halo: as4 = A(t-1) + alpha(t-1)
    for (int idx = tid; idx < 11*44; idx += 512){
      int r = idx/44, c = idx - r*44;
      float v = 0.f;
      if (t > 0 && c < 42){
        int hi2 = h + r - 5, wi = w0 + c - 5;
        if ((unsigned)hi2 < 16u && (unsigned)wi < 64u){
          int p = (hi2<<6) + wi;
          v = aprev[(b<<10)+p] + al[p];
        }
      }
      as4[r][c] = v;
    }
    __syncthreads();
    // ---- im2col: Asb[w][tap] bf16 (pitch 136; taps 121..127 zero)
    #pragma unroll
    for (int u = 0; u < 8; u++){
      int idx = tid + (u<<9);
      int w = idx >> 7, tap = idx & 127;
      float v = 0.f;
      if (tap < 121 && t > 0){
        int ki = tap/11, kj = tap - ki*11;
        v = as4[ki][w + kj];
      }
      Asb[w*136 + tap] = f2bf(v);
    }
    __syncthreads();
    // ---- prefetch transb for epilogue (independent of MFMA; hides latency under MFMA)
    const int mh = wv & 1, ns = wv >> 1;
    float tvv[8][4];
    {
      #pragma unroll
      for (int s = 0; s < 8; s++){
        int d = (ns<<7) + (s<<4) + (lane & 15);
        #pragma unroll
        for (int r = 0; r < 4; r++){
          int w = (mh<<4) + ((lane>>4)<<2) + r;
          int hw = (h<<6) + w0 + w;
          tvv[s][r] = bf2f(transb[((size_t)((b<<10)+hw))*NAD + d]);
        }
      }
    }
    // ---- MFMA stencil: E[32w][512d] = A[32][128] x MtT^T
    const int kg = (lane >> 4) << 3;
    f32x4 acc[8];
    #pragma unroll
    for (int s = 0; s < 8; s++){ acc[s][0]=0.f; acc[s][1]=0.f; acc[s][2]=0.f; acc[s][3]=0.f; }
    if (t > 0){
      const unsigned short* ab = &Asb[((mh<<4) + (lane & 15))*136 + kg];
      #pragma unroll
      for (int k0 = 0; k0 < 128; k0 += 32){
        bf16x8 af = *(const bf16x8*)(ab + k0);
        #pragma unroll
        for (int s = 0; s < 8; s++){
          const unsigned short* brow = MtT + (size_t)((ns<<7) + (s<<4) + (lane & 15))*128 + kg + k0;
          bf16x8 bf = *(const bf16x8*)brow;
          acc[s] = __builtin_amdgcn_mfma_f32_16x16x32_bf16(af, bf, acc[s], 0, 0, 0);
        }
      }
    }
    // ---- epilogue: eo[w][d] = wav[d]*tanh(q[d] + trans + acc)
    const float acb0 = acvb[0];
    #pragma unroll
    for (int s = 0; s < 8; s++){
      int d = (ns<<7) + (s<<4) + (lane & 15);
      float wav = acvW[d];
      float qd = qs[d];
      #pragma unroll
      for (int r = 0; r < 4; r++){
        int w = (mh<<4) + ((lane>>4)<<2) + r;
        eo[w][d] = wav * ftanh(qd + tvv[s][r] + acc[s][r]);
      }
    }
    __syncthreads();
    // ---- reduce: wave wv owns w = wv*4..+3
    float* ecur = ecurb + (b<<10) + (h<<6) + w0;
    #pragma unroll
    for (int k = 0; k < 4; k++){
      int w = (wv<<2) + k;
      float sum = 0.f;
      #pragma unroll
      for (int u = 0; u < 8; u++) sum += eo[w][lane + (u<<6)];
      sum = wred_sum(sum);
      if (lane == 0) ecur[w] = sum + acb0;
    }
    // ---- gru: blocks seg<8; wave owns 4 j; 16 lanes k-split per j
    if (seg < 8 && t < NT-1){
      int j = (seg<<5) + (wv<<2) + (lane>>4);
      int qg = lane & 15;
      const __hip_bfloat162* r0 = whhTjb + (size_t)j*128 + (qg<<3);
      const __hip_bfloat162* r1 = whhTjb + (size_t)(256+j)*128 + (qg<<3);
      const __hip_bfloat162* r2 = whhTjb + (size_t)(512+j)*128 + (qg<<3);
      float sr = 0.f, sz = 0.f, sn = 0.f;
      #pragma unroll
      for (int i = 0; i < 8; i++){
        int kp = (qg<<3) + i;
        float h0 = hq[kp<<1], h1 = hq[(kp<<1)+1];
        __hip_bfloat162 wr = r0[i], wz2 = r1[i], wn = r2[i];
        sr += h0*__bfloat162float(wr.x) + h1*__bfloat162float(wr.y);
        sz += h0*__bfloat162float(wz2.x) + h1*__bfloat162float(wz2.y);
        sn += h0*__bfloat162float(wn.x) + h1*__bfloat162float(wn.y);
      }
      #pragma unroll
      for (int o = 1; o < 16; o <<= 1){
        sr += __shfl_xor(sr, o, 64);
        sz += __shfl_xor(sz, o, 64);
        sn += __shfl_xor(sn, o, 64);
      }
      if (qg == 0){
        int wnext = lab[b*NT + t];
        const float* gg = giW + (size_t)wnext*768;
        float r = fsig(gg[j] + sr + bhh[j]);
        float z = fsig(gg[j+256] + sz + bhh[j+256]);
        float n = ftanh(gg[j+512] + r*(sn + bhh[j+512]));
        hbuf3[((t+1)%3)*2048 + (b<<8) + j] = (1.f - z)*n + z*hq[j];
      }
    }
  }
}

extern "C" void kernel_launch(void* const* d_in, const int* in_sizes, int n_in,
                              void* d_out, int out_size, void* d_ws, size_t ws_size,
                              hipStream_t stream)
{
  const float* cnn  = (const float*)d_in[0];
  const float* cp   = (const float*)d_in[1];
  const float* im   = (const float*)d_in[2];
  const float* iW   = (const float*)d_in[3];
  const float* ib   = (const float*)d_in[4];
  const float* emb  = (const float*)d_in[5];
  const float* wih  = (const float*)d_in[6];
  const float* whh  = (const float*)d_in[7];
  const float* bih  = (const float*)d_in[8];
  const float* bhh  = (const float*)d_in[9];
  const float* ahW  = (const float*)d_in[10];
  const float* ahb  = (const float*)d_in[11];
  const float* acw  = (const float*)d_in[12];
  const float* awW  = (const float*)d_in[13];
  const float* acvW = (const float*)d_in[14];
  const float* acvb = (const float*)d_in[15];
  const float* ecw  = (const float*)d_in[16];
  const float* ecb  = (const float*)d_in[17];
  const float* sW   = (const float*)d_in[18];
  const float* sb   = (const float*)d_in[19];
  const float* ewW  = (const float*)d_in[20];
  const float* ewb2 = (const float*)d_in[21];
  const float* cxW  = (const float*)d_in[22];
  const float* cxb  = (const float*)d_in[23];
  const float* cW   = (const float*)d_in[24];
  const float* cb   = (const float*)d_in[25];
  const float* oW   = (const float*)d_in[26];
  const float* ob   = (const float*)d_in[27];
  const int*   lab  = (const int*)d_in[28];
  float* out = (float*)d_out;
  float* ws = (float*)d_ws;

  float* dmask  = ws + 0;        // 8192
  float* ys     = ws + 8192;     // 8192
  float* xs     = ws + 16384;    // 8192
  float* idt    = ws + 24576;    // 128
  float* msum   = ws + 24704;    // 16
  float* avg    = ws + 24720;    // 5472
  float* cctx   = ws + 30192;    // 2048
  float* hm1    = ws + 32240;    // 2048
  float* hbuf3  = ws + 34288;    // 6144
  float* abuf   = ws + 40432;    // 16384
  float* ebuf   = ws + 56816;    // 16384
  float* giW    = ws + 73200;    // 85248
  float* embwW  = ws + 158448;   // 28416
  float* embwOW = ws + 186864;   // 12352
  unsigned short* MtT = (unsigned short*)(ws + 199216);   // 32768 words
  float* SO     = ws + 231984;   // 28416
  float* CB     = ws + 260400;   // 896
  __hip_bfloat162* whhTjb = (__hip_bfloat162*)(ws + 261296);  // 98304 words
  __hip_bfloat162* ahWTb  = (__hip_bfloat162*)(ws + 359600);  // 65536 words
  unsigned short* cnnT = (unsigned short*)(ws + 425136);  // 2883584 words
  unsigned short* ewbb = (unsigned short*)(ws + 3308720); // 180224 words
  unsigned short* COb  = (unsigned short*)(ws + 3488944); // 45056 words
  unsigned short* transb = (unsigned short*)(ws + 3534000); // 2097152 words
  float* PO     = ws + 5631152;  // 4194304  (total ~39.3 MB)

  k_p0<<<1, 256, 0, stream>>>(im, dmask, msum, ys, xs, idt, abuf);
  k_avg<<<456, 256, 0, stream>>>(cnn, dmask, msum, avg);
  k_init<<<256, 256, 0, stream>>>(avg, iW, ib, cp, cW, cb, hm1, cctx);
  k_wproj<<<dim3(NV, 4), 256, 0, stream>>>(emb, wih, bih, ewW, ewb2, giW, embwW);
  k_ewo<<<NV, 128, 0, stream>>>(embwW, oW, embwOW);
  k_cvt<<<dim3(16, 11, 8), 256, 0, stream>>>(cnn, cnnT);
  k_cvtw<<<(NAD*KPAD + 255)/256, 256, 0, stream>>>(ecw, ewbb);
  k_mma_trans<<<dim3(64, 8), 256, 0, stream>>>(cnnT, ewbb, ecb, ys, xs, idt, transb);
  k_mt<<<121, 256, 0, stream>>>(awW, acw, MtT);
  k_so<<<NV, 256, 0, stream>>>(sW, oW, sb, cxb, cctx, ob, SO, CB);
  k_co<<<dim3(3, 128), 256, 0, stream>>>(cxW, oW, COb);
  k_mma_PO<<<dim3(16, 2, 8), 256, 0, stream>>>(cnnT, COb, PO);
  k_tr<<<128, 256, 0, stream>>>(whh, ahW, whhTjb, ahWTb);
  k_gq0<<<dim3(4, 8), 512, 0, stream>>>(hm1, whh, bhh, giW, hbuf3);

  for (int t = 0; t <= NT; t++){
    k_step<<<256, 512, 0, stream>>>(dmask, MtT, transb, acvW, acvb, PO, SO, CB, embwOW,
                                    giW, lab, whhTjb, bhh, ahWTb, ahb, hbuf3, abuf, ebuf, out, t);
  }
}

// Round 17
// 1064.928 us; speedup vs baseline: 1.2403x; 1.0226x over previous
//
#include <hip/hip_runtime.h>
#include <hip/hip_bf16.h>
#include <math.h>

#define NB 8
#define NC 684
#define NH 16
#define NW 64
#define NHW 1024
#define NHID 256
#define NAD 512
#define NV 111
#define NT 36
#define KPAD 704

typedef __attribute__((ext_vector_type(8))) short bf16x8;
typedef __attribute__((ext_vector_type(4))) float f32x4;

__device__ __forceinline__ float wred_sum(float v){
  #pragma unroll
  for (int o = 32; o > 0; o >>= 1) v += __shfl_xor(v, o, 64);
  return v;
}
__device__ __forceinline__ float fsig(float x){ return 1.f/(1.f + __expf(-x)); }
__device__ __forceinline__ float ftanh(float x){ float e = __expf(2.f*x); return 1.f - 2.f/(e + 1.f); }
__device__ __forceinline__ unsigned short f2bf(float f){
  __hip_bfloat16 h = __float2bfloat16(f);
  return *(unsigned short*)&h;
}
__device__ __forceinline__ float bf2f(unsigned short u){
  return __uint_as_float(((unsigned)u) << 16);
}

// ---------------- P0
__global__ void k_p0(const float* __restrict__ im, float* __restrict__ dmask,
                     float* __restrict__ msum, float* __restrict__ ys, float* __restrict__ xs,
                     float* __restrict__ idt, float* __restrict__ abuf)
{
  const int tid = threadIdx.x;
  for (int i = tid; i < NB*NHW; i += 256){
    int b = i >> 10, hw = i & 1023; int h = hw >> 6, w = hw & 63;
    dmask[i] = im[b*(256*1024) + (h*16)*1024 + (w*16)];
    abuf[i] = 0.f;
  }
  if (tid < 128) idt[tid] = expf(-(float)tid * (9.210340371976184f/128.f));
  __syncthreads();
  if (tid < 8){
    float s = 0.f;
    for (int i = 0; i < NHW; i++) s += dmask[tid*NHW + i];
    msum[tid] = s;
  }
  for (int p = tid; p < NB*NW; p += 256){
    int b = p >> 6, w = p & 63;
    float tot = 0.f;
    for (int h = 0; h < NH; h++) tot += dmask[b*NHW + h*64 + w];
    float inv = 6.283185307179586f/(tot + 1e-6f);
    float run = 0.f;
    for (int h = 0; h < NH; h++){ run += dmask[b*NHW + h*64 + w]; ys[b*NHW + h*64 + w] = run*inv; }
  }
  for (int p = tid; p < NB*NH; p += 256){
    int b = p >> 4, h = p & 15;
    float tot = 0.f;
    for (int w = 0; w < NW; w++) tot += dmask[b*NHW + h*64 + w];
    float inv = 6.283185307179586f/(tot + 1e-6f);
    float run = 0.f;
    for (int w = 0; w < NW; w++){ run += dmask[b*NHW + h*64 + w]; xs[b*NHW + h*64 + w] = run*inv; }
  }
}

// ---------------- P1: masked average
__global__ void k_avg(const float* __restrict__ cnn, const float* __restrict__ dmask,
                      const float* __restrict__ msum, float* __restrict__ avg)
{
  int gid = blockIdx.x*blockDim.x + threadIdx.x;
  int gw = gid >> 6, lane = gid & 63;
  int nw = (gridDim.x*blockDim.x) >> 6;
  for (int ow = gw; ow < NB*NC; ow += nw){
    int b = ow / NC;
    const float* base = cnn + (size_t)ow * NHW;
    const float* dm = dmask + b*NHW;
    float s = 0.f;
    for (int i = lane; i < NHW; i += 64) s += base[i]*dm[i];
    s = wred_sum(s);
    if (lane == 0) avg[ow] = s / msum[b];
  }
}

// ---------------- P2: hidden(-1) + counting_ctx
__global__ void k_init(const float* __restrict__ avg, const float* __restrict__ iW, const float* __restrict__ ib,
                       const float* __restrict__ cp, const float* __restrict__ cW, const float* __restrict__ cb,
                       float* __restrict__ hm1, float* __restrict__ cctx)
{
  int gid = blockIdx.x*blockDim.x + threadIdx.x;
  int gw = gid >> 6, lane = gid & 63;
  int nw = (gridDim.x*blockDim.x) >> 6;
  for (int ow = gw; ow < 2*NB*NHID; ow += nw){
    if (ow < NB*NHID){
      int b = ow >> 8, j = ow & 255;
      float s = 0.f;
      for (int k = lane; k < NC; k += 64) s += avg[b*NC + k]*iW[j*NC + k];
      s = wred_sum(s);
      if (lane == 0) hm1[ow] = tanhf(s + ib[j]);
    } else {
      int o = ow - NB*NHID; int b = o >> 8, j = o & 255;
      float s = 0.f;
      for (int k = lane; k < NV; k += 64) s += cp[b*NV + k]*cW[j*NV + k];
      s = wred_sum(s);
      if (lane == 0) cctx[o] = s + cb[j];
    }
  }
}

// ---------------- P3a: cnnT[b][hw][c] bf16
__global__ __launch_bounds__(256) void k_cvt(const float* __restrict__ cnn, unsigned short* __restrict__ cnnT)
{
  const int hw0 = blockIdx.x << 6, c0 = blockIdx.y << 6, b = blockIdx.z;  // (16, 11, 8)
  __shared__ float T[64][65];
  const int tid = threadIdx.x;
  #pragma unroll
  for (int u = 0; u < 16; u++){
    int idx = tid + (u<<8);
    int cc = idx >> 6, mm = idx & 63;
    int c = c0 + cc;
    T[cc][mm] = (c < NC) ? cnn[((size_t)b*NC + c)*NHW + hw0 + mm] : 0.f;
  }
  __syncthreads();
  #pragma unroll
  for (int r0 = 0; r0 < 64; r0 += 8){
    int hwl = r0 + (tid >> 5);
    int cp = (tid & 31) << 1;
    unsigned u0 = f2bf(T[cp][hwl]);
    unsigned u1 = f2bf(T[cp+1][hwl]);
    *(unsigned*)&cnnT[((size_t)((b<<10) + hw0 + hwl))*KPAD + c0 + cp] = (u1 << 16) | u0;
  }
}

// ---------------- P3b: ewb[d][c] bf16 padded
__global__ void k_cvtw(const float* __restrict__ ew, unsigned short* __restrict__ ewb)
{
  int x = blockIdx.x*256 + threadIdx.x;
  if (x >= NAD*KPAD) return;
  int d = x / KPAD, c = x - d*KPAD;
  float v = (c < NC) ? ew[(size_t)d*NC + c] : 0.f;
  ewb[x] = f2bf(v);
}

// ---------------- P3c: trans(bf16) = MFMA GEMM + bias + pos-emb; 2 m-tiles/wave
__global__ __launch_bounds__(256) void k_mma_trans(const unsigned short* __restrict__ cnnT,
    const unsigned short* __restrict__ ewb, const float* __restrict__ eb,
    const float* __restrict__ ys, const float* __restrict__ xs,
    const float* __restrict__ idt, unsigned short* __restrict__ transb)
{
  const int m0 = blockIdx.x << 7;
  const int n0 = blockIdx.y << 6;
  const int b = m0 >> 10, hw0 = m0 & 1023;
  const int tid = threadIdx.x, lane = tid & 63, wv = tid >> 6;
  const int kgrp = (lane >> 4) << 3;
  const unsigned short* arow0 = cnnT + ((size_t)((b<<10) + hw0 + (wv<<5) + (lane & 15)))*KPAD + kgrp;
  const unsigned short* arow1 = arow0 + (size_t)16*KPAD;
  f32x4 acc[2][4];
  #pragma unroll
  for (int mt=0; mt<2; mt++)
    #pragma unroll
    for (int s = 0; s < 4; s++){ acc[mt][s][0]=0.f; acc[mt][s][1]=0.f; acc[mt][s][2]=0.f; acc[mt][s][3]=0.f; }
  #pragma unroll 2
  for (int k0 = 0; k0 < KPAD; k0 += 32){
    bf16x8 a0 = *(const bf16x8*)(arow0 + k0);
    bf16x8 a1 = *(const bf16x8*)(arow1 + k0);
    #pragma unroll
    for (int s = 0; s < 4; s++){
      const unsigned short* brow = ewb + (size_t)(n0 + (s<<4) + (lane & 15))*KPAD + kgrp + k0;
      bf16x8 bf = *(const bf16x8*)brow;
      acc[0][s] = __builtin_amdgcn_mfma_f32_16x16x32_bf16(a0, bf, acc[0][s], 0, 0, 0);
      acc[1][s] = __builtin_amdgcn_mfma_f32_16x16x32_bf16(a1, bf, acc[1][s], 0, 0, 0);
    }
  }
  #pragma unroll
  for (int mt = 0; mt < 2; mt++){
    #pragma unroll
    for (int r = 0; r < 4; r++){
      int hw = hw0 + (wv<<5) + (mt<<4) + ((lane>>4)<<2) + r;
      float ysv = ys[(b<<10)+hw], xsv = xs[(b<<10)+hw];
      #pragma unroll
      for (int s = 0; s < 4; s++){
        int d = n0 + (s<<4) + (lane & 15);
        float idtv = (d < 256) ? idt[d>>1] : idt[(d-256)>>1];
        float base = (d < 256) ? ysv : xsv;
        float arg = base*idtv;
        float pe = (d & 1) ? cosf(arg) : sinf(arg);
        transb[((size_t)((b<<10)+hw))*NAD + d] = f2bf(acc[mt][s][r] + eb[d] + pe);
      }
    }
  }
}

// ---------------- P4a: per-word projections giW[v][768], embwW[v][256]
__global__ __launch_bounds__(256) void k_wproj(const float* __restrict__ emb, const float* __restrict__ wih,
    const float* __restrict__ bih, const float* __restrict__ ewW, const float* __restrict__ ewb2,
    float* __restrict__ giW, float* __restrict__ embwW)
{
  const int v = blockIdx.x, g = blockIdx.y;  // (111, 4)
  const int tid = threadIdx.x;
  __shared__ float er[256];
  er[tid] = emb[(size_t)v*256 + tid];
  __syncthreads();
  if (g < 3){
    int i = (g<<8) + tid;
    float s = 0.f;
    const float* wr = wih + (size_t)i*256;
    #pragma unroll 4
    for (int k = 0; k < 256; k++) s += er[k]*wr[k];
    giW[(size_t)v*768 + i] = s + bih[i];
  } else {
    float s = 0.f;
    const float* wr = ewW + (size_t)tid*256;
    #pragma unroll 4
    for (int k = 0; k < 256; k++) s += er[k]*wr[k];
    embwW[(size_t)v*256 + tid] = s + ewb2[tid];
  }
}

// ---------------- P4b: embwOW[v][u] = embwW[v]·oW[u]
__global__ __launch_bounds__(128) void k_ewo(const float* __restrict__ embwW, const float* __restrict__ oW,
                                             float* __restrict__ embwOW)
{
  const int v = blockIdx.x;
  const int u = threadIdx.x;
  __shared__ float ew[256];
  ew[u] = embwW[(size_t)v*256 + u];
  ew[128 + u] = embwW[(size_t)v*256 + 128 + u];
  __syncthreads();
  if (u < NV){
    float s = 0.f;
    const float* wr = oW + (size_t)u*256;
    #pragma unroll 4
    for (int k = 0; k < 256; k++) s += ew[k]*wr[k];
    embwOW[v*NV + u] = s;
  }
}

// ---------------- P5: MtT[d][tap] bf16, taps padded to 128
__global__ void k_mt(const float* __restrict__ aw, const float* __restrict__ acw, unsigned short* __restrict__ MtT)
{
  __shared__ float col[512];
  int t = blockIdx.x; int tid = threadIdx.x;   // 121 x 256
  for (int c = tid; c < 512; c += 256) col[c] = acw[(size_t)c*121 + t];
  __syncthreads();
  for (int d = tid; d < 512; d += 256){
    float s = 0.f;
    const float4* r4 = (const float4*)(aw + (size_t)d*512);
    for (int k = 0; k < 128; k++){
      float4 w = r4[k];
      s += col[k*4+0]*w.x + col[k*4+1]*w.y + col[k*4+2]*w.z + col[k*4+3]*w.w;
    }
    MtT[d*128 + t] = f2bf(s);
    if (t == 0){
      #pragma unroll
      for (int p = 121; p < 128; p++) MtT[d*128 + p] = 0;
    }
  }
}

// ---------------- P6: SO = oW@sW; CB
__global__ __launch_bounds__(256) void k_so(const float* __restrict__ sW, const float* __restrict__ oW,
    const float* __restrict__ sb, const float* __restrict__ cxb, const float* __restrict__ cctx,
    const float* __restrict__ ob, float* __restrict__ SO, float* __restrict__ CB)
{
  const int v = blockIdx.x; const int tid = threadIdx.x;
  float acc = 0.f;
  for (int j = 0; j < 256; j++) acc += sW[(size_t)j*256 + tid] * oW[(size_t)v*256 + j];
  SO[(size_t)v*256 + tid] = acc;
  if (tid < 8){
    float s = ob[v];
    for (int j = 0; j < 256; j++) s += (sb[j] + cxb[j] + cctx[tid*256 + j]) * oW[(size_t)v*256 + j];
    CB[tid*NV + v] = s;
  }
}

// ---------------- P8: COb[v][c] bf16
__global__ __launch_bounds__(256) void k_co(const float* __restrict__ cxW, const float* __restrict__ oW,
                                            unsigned short* __restrict__ COb)
{
  const int c = blockIdx.x*256 + threadIdx.x;
  const int v = blockIdx.y;       // 0..127
  if (c >= KPAD) return;
  float acc = 0.f;
  if (v < NV && c < NC){
    for (int j = 0; j < 256; j++) acc += cxW[(size_t)j*NC + c] * oW[(size_t)v*256 + j];
  }
  COb[(size_t)v*KPAD + c] = f2bf(acc);
}

// ---------------- P9: PO = MFMA GEMM
__global__ __launch_bounds__(256) void k_mma_PO(const unsigned short* __restrict__ cnnT,
    const unsigned short* __restrict__ COb, float* __restrict__ PO)
{
  const int m0 = blockIdx.x << 6;
  const int n0 = blockIdx.y << 6;
  const int b = blockIdx.z;
  const int tid = threadIdx.x, lane = tid & 63, wv = tid >> 6;
  const int mrow = m0 + (wv<<4) + (lane & 15);
  const int kgrp = (lane >> 4) << 3;
  const unsigned short* arow = cnnT + ((size_t)((b<<10) + mrow))*KPAD + kgrp;
  f32x4 acc[4];
  #pragma unroll
  for (int s = 0; s < 4; s++){ acc[s][0]=0.f; acc[s][1]=0.f; acc[s][2]=0.f; acc[s][3]=0.f; }
  #pragma unroll 2
  for (int k0 = 0; k0 < KPAD; k0 += 32){
    bf16x8 af = *(const bf16x8*)(arow + k0);
    #pragma unroll
    for (int s = 0; s < 4; s++){
      const unsigned short* brow = COb + (size_t)(n0 + (s<<4) + (lane & 15))*KPAD + kgrp + k0;
      bf16x8 bf = *(const bf16x8*)brow;
      acc[s] = __builtin_amdgcn_mfma_f32_16x16x32_bf16(af, bf, acc[s], 0, 0, 0);
    }
  }
  #pragma unroll
  for (int s = 0; s < 4; s++){
    int v = n0 + (s<<4) + (lane & 15);
    #pragma unroll
    for (int r = 0; r < 4; r++){
      int hw = m0 + (wv<<4) + ((lane>>4)<<2) + r;
      PO[(((size_t)b*128 + v)<<10) + hw] = acc[s][r];
    }
  }
}

// ---------------- gru slice helper — prologue only (fp32)
__device__ __forceinline__ void gru_slice(const float* __restrict__ hs, const float* __restrict__ whh,
    const float* __restrict__ bhh, const float* __restrict__ gg, float* __restrict__ hdst,
    int r, int wid, int lane)
{
  #pragma unroll 1
  for (int jj = 0; jj < 8; jj++){
    int j = (r<<6) + (wid<<3) + jj;
    float sr = 0.f, sz = 0.f, sn = 0.f;
    #pragma unroll
    for (int u = 0; u < 4; u++){
      int k = lane + (u<<6);
      float hv = hs[k];
      sr += hv * whh[(size_t)j*256 + k];
      sz += hv * whh[(size_t)(j+256)*256 + k];
      sn += hv * whh[(size_t)(j+512)*256 + k];
    }
    sr = wred_sum(sr); sz = wred_sum(sz); sn = wred_sum(sn);
    if (lane == 0){
      float rr = 1.f/(1.f + expf(-(gg[j] + sr + bhh[j])));
      float zz = 1.f/(1.f + expf(-(gg[j+256] + sz + bhh[j+256])));
      float nn = tanhf(gg[j+512] + rr*(sn + bhh[j+512]));
      hdst[j] = (1.f - zz)*nn + zz*hs[j];
    }
  }
}

// ---------------- P10: initial GRU (word0 = 1)
__global__ __launch_bounds__(512) void k_gq0(const float* __restrict__ hm1, const float* __restrict__ whh,
    const float* __restrict__ bhh, const float* __restrict__ giW, float* __restrict__ hbuf3)
{
  const int r = blockIdx.x, b = blockIdx.y;
  const int tid = threadIdx.x, lane = tid & 63, wid = tid >> 6;
  __shared__ float hs[256];
  if (tid < 256) hs[tid] = hm1[(b<<8) + tid];
  __syncthreads();
  gru_slice(hs, whh, bhh, giW + 768, hbuf3 + (b<<8), r, wid, lane);
}

// ---------------- P12: bf16-packed weights for in-loop gru/query
__global__ void k_tr(const float* __restrict__ whh, const float* __restrict__ ahW,
                     __hip_bfloat162* __restrict__ whhTjb, __hip_bfloat162* __restrict__ ahWTb)
{
  int i = blockIdx.x*256 + threadIdx.x;
  int stride = gridDim.x*256;
  for (int x = i; x < 3*256*128; x += stride){
    int kp = x & 127, j = (x >> 7) & 255, g = x >> 15;
    float lo = whh[(size_t)((g<<8)+j)*256 + (kp<<1)];
    float hi = whh[(size_t)((g<<8)+j)*256 + (kp<<1) + 1];
    __hip_bfloat162 h2; h2.x = __float2bfloat16(lo); h2.y = __float2bfloat16(hi);
    whhTjb[x] = h2;
  }
  for (int x = i; x < 128*512; x += stride){
    int d = x & 511, kp = x >> 9;
    float lo = ahW[(size_t)d*256 + (kp<<1)];
    float hi = ahW[(size_t)d*256 + (kp<<1) + 1];
    __hip_bfloat162 h2; h2.x = __float2bfloat16(lo); h2.y = __float2bfloat16(hi);
    ahWTb[x] = h2;
  }
}

// ================= per-step kernel: grid 256 (1 block/CU), 512 thr, t = 0..NT =================
// R14 structure with softmax reductions ELIMINATED:
//  alpha = exp(e)*dmask / (sum + 1e-10), shift-free (|e| bounded); per-batch sum assembled
//  cross-launch from 32 per-block partials in triple-buffered esumP[t%3][b][32].
__global__ __launch_bounds__(512) void k_step(
  const float* __restrict__ dmask, const unsigned short* __restrict__ MtT,
  const unsigned short* __restrict__ transb,
  const float* __restrict__ acvW, const float* __restrict__ acvb,
  const float* __restrict__ PO, const float* __restrict__ SO,
  const float* __restrict__ CB, const float* __restrict__ embwOW,
  const float* __restrict__ giW, const int* __restrict__ lab,
  const __hip_bfloat162* __restrict__ whhTjb,
  const float* __restrict__ bhh, const __hip_bfloat162* __restrict__ ahWTb,
  const float* __restrict__ ahb, float* __restrict__ hbuf3,
  float* __restrict__ abuf, float* __restrict__ ebuf,
  float* __restrict__ esumP, float* __restrict__ out, int t)
{
  const int gid = blockIdx.x, tid = threadIdx.x;
  const int lane = tid & 63, wv = tid >> 6;
  const int b = gid >> 5, seg = gid & 31, h = seg >> 1, w0 = (seg & 1) << 5;
  __shared__ float eo[32][516];
  __shared__ float al[1024];
  __shared__ float as4[11][44];
  __shared__ unsigned short Asb[32*136];
  __shared__ float hq[256];
  __shared__ float qs[512];
  __shared__ float part[8];

  const float* eprev = ebuf + (((t+1)&1)<<13);
  float*       ecurb = ebuf + ((t&1)<<13);
  const float* aprev = abuf + (((t+1)&1)<<13);
  float*       acur  = abuf + ((t&1)<<13);

  if (t < NT && tid < 256) hq[tid] = hbuf3[(t%3)*2048 + (b<<8) + tid];

  if (t > 0){
    // ---- alpha from shift-free exp + cross-launch partial sums (no reductions)
    float ssum = 1e-10f;
    {
      const float* ep = esumP + ((t-1)%3)*256 + (b<<5);
      #pragma unroll
      for (int k = 0; k < 32; k++) ssum += ep[k];
    }
    const float inv = 1.f/ssum;
    float e0 = eprev[(b<<10)+tid], e1 = eprev[(b<<10)+512+tid];
    float dm0 = dmask[(b<<10)+tid], dm1 = dmask[(b<<10)+512+tid];
    al[tid] = __expf(e0)*dm0*inv;
    al[512+tid] = __expf(e1)*dm1*inv;
    __syncthreads();
    if (seg == 0 && t < NT){
      acur[(b<<10)+tid]     = aprev[(b<<10)+tid]     + al[tid];
      acur[(b<<10)+512+tid] = aprev[(b<<10)+512+tid] + al[512+tid];
    }
    // ---- prob(t-1): waves 0..3, v = seg + 32*wv
    if (wv < 4){
      int v = seg + (wv<<5);
      if (v < NV){
        int wprev = (t-1 == 0) ? 1 : lab[b*NT + t - 2];
        const float* POr = PO + (((size_t)b*128 + v)<<10);
        const float* hr = hbuf3 + ((t-1)%3)*2048 + (b<<8);
        const float* SOr = SO + (size_t)v*256;
        float a2 = 0.f;
        #pragma unroll
        for (int u = 0; u < 16; u++){ int p = lane + (u<<6); a2 += al[p]*POr[p]; }
        #pragma unroll
        for (int u = 0; u < 4; u++){ int k = lane + (u<<6); a2 += hr[k]*SOr[k]; }
        a2 = wred_sum(a2);
        if (lane == 0)
          out[((size_t)b*NT + (t-1))*NV + v] = a2 + CB[b*NV + v] + embwOW[wprev*NV + v];
      }
    }
  }
  if (t < NT){
    // ---- halo: as4 = A(t-1) + alpha(t-1)
    for (int idx = tid; idx < 11*44; idx += 512){
      int r = idx/44, c = idx - r*44;
      float v = 0.f;
      if (t > 0 && c < 42){
        int hi2 = h + r - 5, wi = w0 + c - 5;
        if ((unsigned)hi2 < 16u && (unsigned)wi < 64u){
          int p = (hi2<<6) + wi;
          v = aprev[(b<<10)+p] + al[p];
        }
      }
      as4[r][c] = v;
    }
    // ---- inline query: q[d=tid] -> qs
    {
      float s2 = 0.f;
      #pragma unroll 4
      for (int kp = 0; kp < 128; kp++){
        __hip_bfloat162 w = ahWTb[(kp<<9) + tid];
        s2 += hq[kp<<1]*__bfloat162float(w.x) + hq[(kp<<1)+1]*__bfloat162float(w.y);
      }
      qs[tid] = s2 + ahb[tid];
    }
    __syncthreads();
    // ---- im2col: Asb[w][tap] bf16 (pitch 136; taps 121..127 zero)
    #pragma unroll
    for (int u = 0; u < 8; u++){
      int idx = tid + (u<<9);
      int w = idx >> 7, tap = idx & 127;
      float v = 0.f;
      if (tap < 121 && t > 0){
        int ki = tap/11, kj = tap - ki*11;
        v = as4[ki][w + kj];
      }
      Asb[w*136 + tap] = f2bf(v);
    }
    __syncthreads();
    // ---- MFMA stencil: E[32w][512d] = A[32][128] x MtT^T
    const int mh = wv & 1, ns = wv >> 1;
    const int kg = (lane >> 4) << 3;
    f32x4 acc[8];
    #pragma unroll
    for (int s = 0; s < 8; s++){ acc[s][0]=0.f; acc[s][1]=0.f; acc[s][2]=0.f; acc[s][3]=0.f; }
    if (t > 0){
      const unsigned short* ab = &Asb[((mh<<4) + (lane & 15))*136 + kg];
      #pragma unroll
      for (int k0 = 0; k0 < 128; k0 += 32){
        bf16x8 af = *(const bf16x8*)(ab + k0);
        #pragma unroll
        for (int s = 0; s < 8; s++){
          const unsigned short* brow = MtT + (size_t)((ns<<7) + (s<<4) + (lane & 15))*128 + kg + k0;
          bf16x8 bf = *(const bf16x8*)brow;
          acc[s] = __builtin_amdgcn_mfma_f32_16x16x32_bf16(af, bf, acc[s], 0, 0, 0);
        }
      }
    }
    // ---- epilogue: eo[w][d] = wav[d]*tanh(q[d] + trans + acc)
    const float acb0 = acvb[0];
    #pragma unroll
    for (int s = 0; s < 8; s++){
      int d = (ns<<7) + (s<<4) + (lane & 15);
      float wav = acvW[d];
      float qd = qs[d];
      #pragma unroll
      for (int r = 0; r < 4; r++){
        int w = (mh<<4) + ((lane>>4)<<2) + r;
        int hw = (h<<6) + w0 + w;
        float tv = bf2f(transb[((size_t)((b<<10)+hw))*NAD + d]);
        eo[w][d] = wav * ftanh(qd + tv + acc[s][r]);
      }
    }
    __syncthreads();
    // ---- reduce: wave wv owns w = wv*4..+3; also accumulate exp partial for next step
    float* ecur = ecurb + (b<<10) + (h<<6) + w0;
    float pe = 0.f;
    #pragma unroll
    for (int k = 0; k < 4; k++){
      int w = (wv<<2) + k;
      float sum = 0.f;
      #pragma unroll
      for (int u = 0; u < 8; u++) sum += eo[w][lane + (u<<6)];
      sum = wred_sum(sum);
      if (lane == 0){
        float ev = sum + acb0;
        ecur[w] = ev;
        pe += __expf(ev)*dmask[(b<<10) + (h<<6) + w0 + w];
      }
    }
    if (lane == 0) part[wv] = pe;
    __syncthreads();
    if (tid == 0){
      float tp = 0.f;
      #pragma unroll
      for (int k = 0; k < 8; k++) tp += part[k];
      esumP[(t%3)*256 + (b<<5) + seg] = tp;
    }
    // ---- gru: blocks seg<8; wave owns 4 j; 16 lanes k-split per j
    if (seg < 8 && t < NT-1){
      int j = (seg<<5) + (wv<<2) + (lane>>4);
      int qg = lane & 15;
      const __hip_bfloat162* r0 = whhTjb + (size_t)j*128 + (qg<<3);
      const __hip_bfloat162* r1 = whhTjb + (size_t)(256+j)*128 + (qg<<3);
      const __hip_bfloat162* r2 = whhTjb + (size_t)(512+j)*128 + (qg<<3);
      float sr = 0.f, sz = 0.f, sn = 0.f;
      #pragma unroll
      for (int i = 0; i < 8; i++){
        int kp = (qg<<3) + i;
        float h0 = hq[kp<<1], h1 = hq[(kp<<1)+1];
        __hip_bfloat162 wr = r0[i], wz2 = r1[i], wn = r2[i];
        sr += h0*__bfloat162float(wr.x) + h1*__bfloat162float(wr.y);
        sz += h0*__bfloat162float(wz2.x) + h1*__bfloat162float(wz2.y);
        sn += h0*__bfloat162float(wn.x) + h1*__bfloat162float(wn.y);
      }
      #pragma unroll
      for (int o = 1; o < 16; o <<= 1){
        sr += __shfl_xor(sr, o, 64);
        sz += __shfl_xor(sz, o, 64);
        sn += __shfl_xor(sn, o, 64);
      }
      if (qg == 0){
        int wnext = lab[b*NT + t];
        const float* gg = giW + (size_t)wnext*768;
        float r = fsig(gg[j] + sr + bhh[j]);
        float z = fsig(gg[j+256] + sz + bhh[j+256]);
        float n = ftanh(gg[j+512] + r*(sn + bhh[j+512]));
        hbuf3[((t+1)%3)*2048 + (b<<8) + j] = (1.f - z)*n + z*hq[j];
      }
    }
  }
}

extern "C" void kernel_launch(void* const* d_in, const int* in_sizes, int n_in,
                              void* d_out, int out_size, void* d_ws, size_t ws_size,
                              hipStream_t stream)
{
  const float* cnn  = (const float*)d_in[0];
  const float* cp   = (const float*)d_in[1];
  const float* im   = (const float*)d_in[2];
  const float* iW   = (const float*)d_in[3];
  const float* ib   = (const float*)d_in[4];
  const float* emb  = (const float*)d_in[5];
  const float* wih  = (const float*)d_in[6];
  const float* whh  = (const float*)d_in[7];
  const float* bih  = (const float*)d_in[8];
  const float* bhh  = (const float*)d_in[9];
  const float* ahW  = (const float*)d_in[10];
  const float* ahb  = (const float*)d_in[11];
  const float* acw  = (const float*)d_in[12];
  const float* awW  = (const float*)d_in[13];
  const float* acvW = (const float*)d_in[14];
  const float* acvb = (const float*)d_in[15];
  const float* ecw  = (const float*)d_in[16];
  const float* ecb  = (const float*)d_in[17];
  const float* sW   = (const float*)d_in[18];
  const float* sb   = (const float*)d_in[19];
  const float* ewW  = (const float*)d_in[20];
  const float* ewb2 = (const float*)d_in[21];
  const float* cxW  = (const float*)d_in[22];
  const float* cxb  = (const float*)d_in[23];
  const float* cW   = (const float*)d_in[24];
  const float* cb   = (const float*)d_in[25];
  const float* oW   = (const float*)d_in[26];
  const float* ob   = (const float*)d_in[27];
  const int*   lab  = (const int*)d_in[28];
  float* out = (float*)d_out;
  float* ws = (float*)d_ws;

  float* dmask  = ws + 0;        // 8192
  float* ys     = ws + 8192;     // 8192
  float* xs     = ws + 16384;    // 8192
  float* idt    = ws + 24576;    // 128
  float* msum   = ws + 24704;    // 16
  float* avg    = ws + 24720;    // 5472
  float* cctx   = ws + 30192;    // 2048
  float* hm1    = ws + 32240;    // 2048
  float* hbuf3  = ws + 34288;    // 6144
  float* abuf   = ws + 40432;    // 16384
  float* ebuf   = ws + 56816;    // 16384
  float* giW    = ws + 73200;    // 85248
  float* embwW  = ws + 158448;   // 28416
  float* embwOW = ws + 186864;   // 12352
  unsigned short* MtT = (unsigned short*)(ws + 199216);   // 32768 words
  float* SO     = ws + 231984;   // 28416
  float* CB     = ws + 260400;   // 896
  __hip_bfloat162* whhTjb = (__hip_bfloat162*)(ws + 261296);  // 98304 words
  __hip_bfloat162* ahWTb  = (__hip_bfloat162*)(ws + 359600);  // 65536 words
  unsigned short* cnnT = (unsigned short*)(ws + 425136);  // 2883584 words
  unsigned short* ewbb = (unsigned short*)(ws + 3308720); // 180224 words
  unsigned short* COb  = (unsigned short*)(ws + 3488944); // 45056 words
  unsigned short* transb = (unsigned short*)(ws + 3534000); // 2097152 words
  float* PO     = ws + 5631152;  // 4194304
  float* esumP  = ws + 9825456;  // 768  (total ~39.3 MB)

  k_p0<<<1, 256, 0, stream>>>(im, dmask, msum, ys, xs, idt, abuf);
  k_avg<<<456, 256, 0, stream>>>(cnn, dmask, msum, avg);
  k_init<<<256, 256, 0, stream>>>(avg, iW, ib, cp, cW, cb, hm1, cctx);
  k_wproj<<<dim3(NV, 4), 256, 0, stream>>>(emb, wih, bih, ewW, ewb2, giW, embwW);
  k_ewo<<<NV, 128, 0, stream>>>(embwW, oW, embwOW);
  k_cvt<<<dim3(16, 11, 8), 256, 0, stream>>>(cnn, cnnT);
  k_cvtw<<<(NAD*KPAD + 255)/256, 256, 0, stream>>>(ecw, ewbb);
  k_mma_trans<<<dim3(64, 8), 256, 0, stream>>>(cnnT, ewbb, ecb, ys, xs, idt, transb);
  k_mt<<<121, 256, 0, stream>>>(awW, acw, MtT);
  k_so<<<NV, 256, 0, stream>>>(sW, oW, sb, cxb, cctx, ob, SO, CB);
  k_co<<<dim3(3, 128), 256, 0, stream>>>(cxW, oW, COb);
  k_mma_PO<<<dim3(16, 2, 8), 256, 0, stream>>>(cnnT, COb, PO);
  k_tr<<<128, 256, 0, stream>>>(whh, ahW, whhTjb, ahWTb);
  k_gq0<<<dim3(4, 8), 512, 0, stream>>>(hm1, whh, bhh, giW, hbuf3);

  for (int t = 0; t <= NT; t++){
    k_step<<<256, 512, 0, stream>>>(dmask, MtT, transb, acvW, acvb, PO, SO, CB, embwOW,
                                    giW, lab, whhTjb, bhh, ahWTb, ahb, hbuf3, abuf, ebuf,
                                    esumP, out, t);
  }
}